// Round 6
// baseline (209.957 us; speedup 1.0000x reference)
//
#include <hip/hip_runtime.h>

#define N 768
#define E 24576
#define CH 8             // edges per staged LDS chunk
#define CHF (CH * 64)    // floats per chunk (512 = 2 KB)

// ---------------------------------------------------------------------------
// Workspace init: winner = -1, deg/curs = 0. Replaces 3 memset dispatches.
// ---------------------------------------------------------------------------
__global__ __launch_bounds__(256) void init_ws(int4* __restrict__ winner4,
                                               int* __restrict__ deg,
                                               int* __restrict__ curs) {
  const int t = blockIdx.x * 256 + threadIdx.x;  // 576*256 = 147456 = N*N/4
  winner4[t] = make_int4(-1, -1, -1, -1);
  if (t < 1024) { deg[t] = 0; curs[t] = 0; }
}

// ---------------------------------------------------------------------------
// Transpose mtr [i][j][8] -> mtrT [j][i][8] so the contraction reads rows.
// ---------------------------------------------------------------------------
__global__ __launch_bounds__(256) void transpose_mtr(
    const float* __restrict__ mtr, float* __restrict__ mtrT) {
  __shared__ float lds[16][16 * 8 + 4];
  const int r = threadIdx.x >> 4;  // 0..15
  const int c = threadIdx.x & 15;  // 0..15
  const size_t i0 = (size_t)blockIdx.y * 16;
  const size_t j0 = (size_t)blockIdx.x * 16;

  const float4* src = (const float4*)(mtr + ((i0 + r) * N + (j0 + c)) * 8);
  float4 a = src[0], b = src[1];
  *(float4*)&lds[r][c * 8 + 0] = a;
  *(float4*)&lds[r][c * 8 + 4] = b;
  __syncthreads();
  float4* dst = (float4*)(mtrT + ((j0 + r) * N + (i0 + c)) * 8);
  dst[0] = *(float4*)&lds[c][r * 8 + 0];
  dst[1] = *(float4*)&lds[c][r * 8 + 4];
}

// ---------------------------------------------------------------------------
// Pre-pass: winner marking (last-write-wins .set semantics) + dst-degree.
// ---------------------------------------------------------------------------
__global__ __launch_bounds__(256) void edge_prep(
    const int* __restrict__ ei, int* __restrict__ winner,
    int* __restrict__ deg) {
  const int e = blockIdx.x * 256 + threadIdx.x;
  if (e >= E) return;
  const int s = ei[e];
  const int d = ei[E + e];
  atomicMax(&winner[(size_t)s * N + d], e);
  atomicAdd(&deg[d], 1);
}

// ---------------------------------------------------------------------------
// Exclusive scan of deg[0..768) -> offs[0..768]. One wave, 12 values/lane.
// ---------------------------------------------------------------------------
__global__ void scan_offs(const int* __restrict__ deg, int* __restrict__ offs) {
  const int lane = threadIdx.x;  // 64 threads
  int v[12];
  int s = 0;
#pragma unroll
  for (int z = 0; z < 12; ++z) {
    v[z] = deg[lane * 12 + z];
    s += v[z];
  }
  int inc = s;
#pragma unroll
  for (int d = 1; d < 64; d <<= 1) {
    int t = __shfl_up(inc, d, 64);
    if (lane >= d) inc += t;
  }
  int run = inc - s;  // exclusive prefix of this lane's chunk
#pragma unroll
  for (int z = 0; z < 12; ++z) {
    run += v[z];
    offs[lane * 12 + z + 1] = run;
  }
  if (lane == 0) offs[0] = 0;
}

// ---------------------------------------------------------------------------
// Assign CSR slots to WINNING edges: epos[e] = slot (or -1), jlist[slot] = src.
// ---------------------------------------------------------------------------
__global__ __launch_bounds__(256) void scatter_pos(
    const int* __restrict__ ei, const int* __restrict__ winner,
    const int* __restrict__ offs, int* __restrict__ curs,
    int* __restrict__ jlist, int* __restrict__ epos) {
  const int e = blockIdx.x * 256 + threadIdx.x;
  if (e >= E) return;
  const int s = ei[e];
  const int d = ei[E + e];
  if (winner[(size_t)s * N + d] != e) { epos[e] = -1; return; }
  const int pos = offs[d] + atomicAdd(&curs[d], 1);
  jlist[pos] = s;
  epos[e] = pos;
}

// ---------------------------------------------------------------------------
// Edge MLP: 20 -> 32 -> 32 -> 32 -> 64. Winners write their 8x8 block
// directly into CSR order (Mlist[pos]); losers skip the MLP entirely.
// (256,2): allow up to 256 VGPR — ~90 live floats, must not spill.
// ---------------------------------------------------------------------------
__global__ __launch_bounds__(256, 2) void edge_mlp(
    const float* __restrict__ feat, const int* __restrict__ ei,
    const float* __restrict__ ea, const int* __restrict__ epos,
    const float* __restrict__ w0, const float* __restrict__ b0,
    const float* __restrict__ w1, const float* __restrict__ b1,
    const float* __restrict__ w2, const float* __restrict__ b2,
    const float* __restrict__ w3, const float* __restrict__ b3,
    float* __restrict__ Mlist) {
  const int e = blockIdx.x * 256 + threadIdx.x;
  if (e >= E) return;
  const int pos = epos[e];
  if (pos < 0) return;
  const int s = ei[e];
  const int d = ei[E + e];

  float x[20];
  {
    float4 t = *(const float4*)(ea + (size_t)e * 4);
    x[0] = t.x; x[1] = t.y; x[2] = t.z; x[3] = t.w;
    float4 f0 = *(const float4*)(feat + (size_t)s * 8);
    float4 f1 = *(const float4*)(feat + (size_t)s * 8 + 4);
    x[4] = f0.x; x[5] = f0.y; x[6] = f0.z; x[7] = f0.w;
    x[8] = f1.x; x[9] = f1.y; x[10] = f1.z; x[11] = f1.w;
    float4 g0 = *(const float4*)(feat + (size_t)d * 8);
    float4 g1 = *(const float4*)(feat + (size_t)d * 8 + 4);
    x[12] = g0.x; x[13] = g0.y; x[14] = g0.z; x[15] = g0.w;
    x[16] = g1.x; x[17] = g1.y; x[18] = g1.z; x[19] = g1.w;
  }

  float h[32];
#pragma unroll
  for (int o = 0; o < 32; ++o) {
    float acc = b0[o];
#pragma unroll
    for (int c = 0; c < 20; ++c) acc = fmaf(w0[o * 20 + c], x[c], acc);
    h[o] = fmaxf(acc, 0.f);
  }

  float g[32];
#pragma unroll
  for (int o = 0; o < 32; ++o) {
    float acc = b1[o];
#pragma unroll
    for (int c = 0; c < 32; ++c) acc = fmaf(w1[o * 32 + c], h[c], acc);
    g[o] = fmaxf(acc, 0.f);
  }
  float h2[32];
#pragma unroll
  for (int o = 0; o < 32; ++o) {
    float acc = b2[o];
#pragma unroll
    for (int c = 0; c < 32; ++c) acc = fmaf(w2[o * 32 + c], g[c], acc);
    h2[o] = fmaxf(acc, 0.f);
  }

  float* erow = Mlist + (size_t)pos * 64;
#pragma unroll
  for (int o4 = 0; o4 < 16; ++o4) {
    float r[4];
#pragma unroll
    for (int q = 0; q < 4; ++q) {
      const int o = o4 * 4 + q;
      float acc = b3[o];
#pragma unroll
      for (int c = 0; c < 32; ++c) acc = fmaf(w3[o * 32 + c], h2[c], acc);
      r[q] = acc;
    }
    *(float4*)(erow + o4 * 4) = make_float4(r[0], r[1], r[2], r[3]);
  }
}

// ---------------------------------------------------------------------------
// Walk contraction v5 — LDS-staged M stream (global_load_lds, double-buffered).
// ---------------------------------------------------------------------------
__device__ __forceinline__ void gload_lds16(const float* g, float* l) {
  __builtin_amdgcn_global_load_lds(
      (const __attribute__((address_space(1))) unsigned int*)g,
      (__attribute__((address_space(3))) unsigned int*)l, 16, 0, 0);
}

__global__ __launch_bounds__(128) void contract5(
    const float* __restrict__ mtrT, const float* __restrict__ Mlist,
    const int* __restrict__ jlist, const int* __restrict__ offs,
    const int* __restrict__ wcnt, float* __restrict__ WT) {
  __shared__ __align__(16) float Ms[2][CHF];

  const int b = blockIdx.x;
  const int g = (b & 7) * 576 + (b >> 3);  // XCD-chunked: 4608 = 8 x 576
  const int t = g / 768;                   // i-tile 0..5
  const int k = g % 768;
  const int tid = threadIdx.x;             // 0..127
  const int lane = tid & 63;
  const int i = t * 128 + tid;

  const int base = offs[k];
  const int cnt = wcnt[k];
  const int nch = (cnt + CH - 1) / CH;

  float acc[8];
#pragma unroll
  for (int q = 0; q < 8; ++q) acc[q] = 0.f;

#define STAGE(ch_)                                                          \
  do {                                                                      \
    const int _c = (ch_);                                                   \
    if (_c * CH + (tid >> 4) < cnt) {                                       \
      const float* _g = Mlist + ((size_t)(base + _c * CH) * 64) + tid * 4;  \
      float* _l = &Ms[_c & 1][(tid >> 6) * 256];                            \
      gload_lds16(_g, _l);                                                  \
    }                                                                       \
  } while (0)

  if (nch > 0) STAGE(0);
  __syncthreads();

  int jv = 0;
#pragma unroll 1
  for (int ch = 0; ch < nch; ++ch) {
    if ((ch & 7) == 0) {  // refresh 64 j's per super-chunk
      const int o = ch * CH + lane;
      jv = (o < cnt) ? jlist[base + o] : 0;
    }
    if (ch + 1 < nch) STAGE(ch + 1);

    const float* Mb = &Ms[ch & 1][0];
    const int lim = min(CH, cnt - ch * CH);
#pragma unroll 2
    for (int q = 0; q < lim; ++q) {
      const int xx = ch * CH + q;
      const int j = __builtin_amdgcn_readlane(jv, xx & 63);

      const float* P = mtrT + ((size_t)j * N + i) * 8;
      float4 a = ((const float4*)P)[0];
      float4 bb = ((const float4*)P)[1];
      float v[8] = {a.x, a.y, a.z, a.w, bb.x, bb.y, bb.z, bb.w};

#pragma unroll
      for (int c = 0; c < 8; ++c) {
        float4 m0 = *(const float4*)&Mb[q * 64 + c * 8];
        float4 m1 = *(const float4*)&Mb[q * 64 + c * 8 + 4];
        acc[0] = fmaf(v[c], m0.x, acc[0]);
        acc[1] = fmaf(v[c], m0.y, acc[1]);
        acc[2] = fmaf(v[c], m0.z, acc[2]);
        acc[3] = fmaf(v[c], m0.w, acc[3]);
        acc[4] = fmaf(v[c], m1.x, acc[4]);
        acc[5] = fmaf(v[c], m1.y, acc[5]);
        acc[6] = fmaf(v[c], m1.z, acc[6]);
        acc[7] = fmaf(v[c], m1.w, acc[7]);
      }
    }
    __syncthreads();  // drains vmcnt (stage) before buffer reuse
  }
#undef STAGE

  float* dst = WT + ((size_t)k * N + i) * 8;
  *(float4*)(dst + 0) = make_float4(acc[0] * 0.125f, acc[1] * 0.125f,
                                    acc[2] * 0.125f, acc[3] * 0.125f);
  *(float4*)(dst + 4) = make_float4(acc[4] * 0.125f, acc[5] * 0.125f,
                                    acc[6] * 0.125f, acc[7] * 0.125f);
}

// ---------------------------------------------------------------------------
// Per-node precompute for out_mlp layer 0.
// ---------------------------------------------------------------------------
__global__ __launch_bounds__(256) void node_pre(
    const float* __restrict__ feat, const float* __restrict__ w0,
    const float* __restrict__ b0, float* __restrict__ preK,
    float* __restrict__ preI) {
  const int n = blockIdx.x * 256 + threadIdx.x;
  if (n >= N) return;
  float f[8];
  float4 f0 = ((const float4*)(feat + (size_t)n * 8))[0];
  float4 f1 = ((const float4*)(feat + (size_t)n * 8))[1];
  f[0] = f0.x; f[1] = f0.y; f[2] = f0.z; f[3] = f0.w;
  f[4] = f1.x; f[5] = f1.y; f[6] = f1.z; f[7] = f1.w;
#pragma unroll
  for (int o = 0; o < 32; ++o) {
    float sK = 0.f, sI = b0[o];
#pragma unroll
    for (int c = 0; c < 8; ++c) {
      sK = fmaf(w0[o * 33 + 16 + c], f[c], sK);
      sI = fmaf(w0[o * 33 + 24 + c], f[c], sI);
    }
    preK[n * 32 + o] = sK;
    preI[n * 32 + o] = sI;
  }
}

// ---------------------------------------------------------------------------
// Output MLP v3: x = [WT[k][i], WT[i][k], featK (pre), featI (pre), eye]
// k-fastest thread mapping (coalesced mtr/out); both WT slabs staged via LDS
// (coalesced global reads, <=2-way LDS conflicts); layers fully unrolled;
// (256,4): VGPR cap 128 — no spills at ~100 live floats.
// ---------------------------------------------------------------------------
__global__ __launch_bounds__(256, 4) void out_mlp(
    const float* __restrict__ mtr, const float* __restrict__ WT,
    const float* __restrict__ preK, const float* __restrict__ preI,
    const float* __restrict__ w0,
    const float* __restrict__ w1, const float* __restrict__ b1,
    const float* __restrict__ w2, const float* __restrict__ b2,
    const float* __restrict__ w3, const float* __restrict__ b3,
    float* __restrict__ out) {
  __shared__ float sA[16][132];   // sA[r][c*8+q] = WT[k0+r][i0+c][q]
  __shared__ float sBT[16][132];  // sBT[kk][r*8+q] = WT[i0+r][k0+kk][q]
  __shared__ float sK[16][33], sI[16][33];

  const int kl = threadIdx.x & 15;  // k fastest -> coalesced out/mtr
  const int il = threadIdx.x >> 4;
  const int k0 = blockIdx.x * 16, i0 = blockIdx.y * 16;
  const int i = i0 + il;
  const int k = k0 + kl;

  // ---- stage preK (by k) / preI (by i) ----
  {
    const int r = threadIdx.x >> 4;
    const int c2 = (threadIdx.x & 15) * 2;
    const float* gK = preK + (size_t)(k0 + r) * 32;
    const float* gI = preI + (size_t)(i0 + r) * 32;
    sK[r][c2] = gK[c2]; sK[r][c2 + 1] = gK[c2 + 1];
    sI[r][c2] = gI[c2]; sI[r][c2 + 1] = gI[c2 + 1];
  }
  // ---- stage WT slabs (coalesced rows; slab B stored transposed) ----
  {
    const int r = threadIdx.x >> 4;  // row in slab
    const int f = threadIdx.x & 15;  // float4-pair index in 128-float row
    const float* gA = WT + ((size_t)(k0 + r) * N + i0) * 8;
    float4 a0 = ((const float4*)gA)[2 * f];
    float4 a1 = ((const float4*)gA)[2 * f + 1];
    *(float4*)&sA[r][f * 8] = a0;
    *(float4*)&sA[r][f * 8 + 4] = a1;
    const float* gB = WT + ((size_t)(i0 + r) * N + k0) * 8;
    float4 b0v = ((const float4*)gB)[2 * f];  // = WT[i0+r][k0+f][0..3]
    float4 b1v = ((const float4*)gB)[2 * f + 1];
    *(float4*)&sBT[f][r * 8] = b0v;
    *(float4*)&sBT[f][r * 8 + 4] = b1v;
  }
  __syncthreads();

  float x[16];
  {
    float4 a0 = *(const float4*)&sA[kl][il * 8];
    float4 a1 = *(const float4*)&sA[kl][il * 8 + 4];
    float4 c0 = *(const float4*)&sBT[kl][il * 8];
    float4 c1 = *(const float4*)&sBT[kl][il * 8 + 4];
    x[0] = a0.x; x[1] = a0.y; x[2] = a0.z; x[3] = a0.w;
    x[4] = a1.x; x[5] = a1.y; x[6] = a1.z; x[7] = a1.w;
    x[8] = c0.x; x[9] = c0.y; x[10] = c0.z; x[11] = c0.w;
    x[12] = c1.x; x[13] = c1.y; x[14] = c1.z; x[15] = c1.w;
  }
  const float eye = (i == k) ? 1.f : 0.f;

  float h[32];
#pragma unroll
  for (int o = 0; o < 32; ++o) {
    float acc = sK[kl][o] + sI[il][o];
    acc = fmaf(eye, w0[o * 33 + 32], acc);
#pragma unroll
    for (int c = 0; c < 16; ++c) acc = fmaf(w0[o * 33 + c], x[c], acc);
    h[o] = fmaxf(acc, 0.f);
  }

  float g[32];
#pragma unroll
  for (int o = 0; o < 32; ++o) {
    float acc = b1[o];
#pragma unroll
    for (int c = 0; c < 32; ++c) acc = fmaf(w1[o * 32 + c], h[c], acc);
    g[o] = fmaxf(acc, 0.f);
  }
  float h2[32];
#pragma unroll
  for (int o = 0; o < 32; ++o) {
    float acc = b2[o];
#pragma unroll
    for (int c = 0; c < 32; ++c) acc = fmaf(w2[o * 32 + c], g[c], acc);
    h2[o] = fmaxf(acc, 0.f);
  }

  const size_t idx = ((size_t)i * N + k) * 8;
  float r[8];
#pragma unroll
  for (int t = 0; t < 8; ++t) {
    float acc = b3[t];
#pragma unroll
    for (int c = 0; c < 32; ++c) acc = fmaf(w3[t * 32 + c], h2[c], acc);
    r[t] = acc;
  }
  float4 m0 = *(const float4*)(mtr + idx);
  float4 m1 = *(const float4*)(mtr + idx + 4);
  *(float4*)(out + idx + 0) = make_float4(m0.x + r[0], m0.y + r[1],
                                          m0.z + r[2], m0.w + r[3]);
  *(float4*)(out + idx + 4) = make_float4(m1.x + r[4], m1.y + r[5],
                                          m1.z + r[6], m1.w + r[7]);
}

// ---------------------------------------------------------------------------
extern "C" void kernel_launch(void* const* d_in, const int* in_sizes, int n_in,
                              void* d_out, int out_size, void* d_ws,
                              size_t ws_size, hipStream_t stream) {
  const float* mtr  = (const float*)d_in[0];
  const float* feat = (const float*)d_in[1];
  const int*   ei   = (const int*)d_in[2];
  const float* ea   = (const float*)d_in[3];
  const float* ew0 = (const float*)d_in[4];
  const float* eb0 = (const float*)d_in[5];
  const float* ew1 = (const float*)d_in[6];
  const float* eb1 = (const float*)d_in[7];
  const float* ew2 = (const float*)d_in[8];
  const float* eb2 = (const float*)d_in[9];
  const float* ew3 = (const float*)d_in[10];
  const float* eb3 = (const float*)d_in[11];
  const float* ow0 = (const float*)d_in[12];
  const float* ob0 = (const float*)d_in[13];
  const float* ow1 = (const float*)d_in[14];
  const float* ob1 = (const float*)d_in[15];
  const float* ow2 = (const float*)d_in[16];
  const float* ob2 = (const float*)d_in[17];
  const float* ow3 = (const float*)d_in[18];
  const float* ob3 = (const float*)d_in[19];
  float* out = (float*)d_out;

  char* ws = (char*)d_ws;
  float* Mlist = (float*)ws; ws += (size_t)(E + 16) * 64 * 4;  // 6.3 MB (+pad)
  float* mtrT  = (float*)ws; ws += (size_t)N * N * 8 * 4;      // 18.87 MB
  float* WT    = (float*)ws; ws += (size_t)N * N * 8 * 4;      // 18.87 MB
  int* winner  = (int*)ws;   ws += (size_t)N * N * 4;          // 2.36 MB
  int* deg     = (int*)ws;   ws += 1024 * 4;
  int* offs    = (int*)ws;   ws += 1024 * 4;
  int* curs    = (int*)ws;   ws += 1024 * 4;
  int* jlist   = (int*)ws;   ws += (size_t)E * 4;              // 98 KB
  int* epos    = (int*)ws;   ws += (size_t)E * 4;              // 98 KB
  float* preK  = (float*)ws; ws += (size_t)N * 32 * 4;         // 98 KB
  float* preI  = (float*)ws; ws += (size_t)N * 32 * 4;         // 98 KB

  init_ws<<<576, 256, 0, stream>>>((int4*)winner, deg, curs);
  edge_prep<<<E / 256, 256, 0, stream>>>(ei, winner, deg);
  scan_offs<<<1, 64, 0, stream>>>(deg, offs);
  scatter_pos<<<E / 256, 256, 0, stream>>>(ei, winner, offs, curs, jlist, epos);
  transpose_mtr<<<dim3(48, 48), 256, 0, stream>>>(mtr, mtrT);
  node_pre<<<3, 256, 0, stream>>>(feat, ow0, ob0, preK, preI);
  edge_mlp<<<E / 256, 256, 0, stream>>>(feat, ei, ea, epos, ew0, eb0, ew1, eb1,
                                        ew2, eb2, ew3, eb3, Mlist);
  contract5<<<4608, 128, 0, stream>>>(mtrT, Mlist, jlist, offs, curs, WT);
  out_mlp<<<dim3(48, 48), 256, 0, stream>>>(mtr, WT, preK, preI, ow0, ow1, ob1,
                                            ow2, ob2, ow3, ob3, out);
}

// Round 7
// 169.493 us; speedup vs baseline: 1.2387x; 1.2387x over previous
//
#include <hip/hip_runtime.h>

#define N 768
#define E 24576
#define CH 8             // edges per staged LDS chunk
#define CHF (CH * 64)    // floats per chunk (512 = 2 KB)

typedef __attribute__((ext_vector_type(8))) short bf16x8;
typedef __attribute__((ext_vector_type(4))) float f32x4;

// ---------------------------------------------------------------------------
// Workspace init: winner = -1, deg/curs = 0.
// ---------------------------------------------------------------------------
__global__ __launch_bounds__(256) void init_ws(int4* __restrict__ winner4,
                                               int* __restrict__ deg,
                                               int* __restrict__ curs) {
  const int t = blockIdx.x * 256 + threadIdx.x;  // 576*256 = N*N/4
  winner4[t] = make_int4(-1, -1, -1, -1);
  if (t < 1024) { deg[t] = 0; curs[t] = 0; }
}

// ---------------------------------------------------------------------------
// Transpose mtr [i][j][8] -> mtrT [j][i][8].
// ---------------------------------------------------------------------------
__global__ __launch_bounds__(256) void transpose_mtr(
    const float* __restrict__ mtr, float* __restrict__ mtrT) {
  __shared__ float lds[16][16 * 8 + 4];
  const int r = threadIdx.x >> 4;
  const int c = threadIdx.x & 15;
  const size_t i0 = (size_t)blockIdx.y * 16;
  const size_t j0 = (size_t)blockIdx.x * 16;

  const float4* src = (const float4*)(mtr + ((i0 + r) * N + (j0 + c)) * 8);
  float4 a = src[0], b = src[1];
  *(float4*)&lds[r][c * 8 + 0] = a;
  *(float4*)&lds[r][c * 8 + 4] = b;
  __syncthreads();
  float4* dst = (float4*)(mtrT + ((j0 + r) * N + (i0 + c)) * 8);
  dst[0] = *(float4*)&lds[c][r * 8 + 0];
  dst[1] = *(float4*)&lds[c][r * 8 + 4];
}

// ---------------------------------------------------------------------------
// Pre-pass: winner marking + dst-degree histogram.
// ---------------------------------------------------------------------------
__global__ __launch_bounds__(256) void edge_prep(
    const int* __restrict__ ei, int* __restrict__ winner,
    int* __restrict__ deg) {
  const int e = blockIdx.x * 256 + threadIdx.x;
  if (e >= E) return;
  const int s = ei[e];
  const int d = ei[E + e];
  atomicMax(&winner[(size_t)s * N + d], e);
  atomicAdd(&deg[d], 1);
}

// ---------------------------------------------------------------------------
// Exclusive scan of deg[0..768) -> offs[0..768]. One wave, 12 values/lane.
// ---------------------------------------------------------------------------
__global__ void scan_offs(const int* __restrict__ deg, int* __restrict__ offs) {
  const int lane = threadIdx.x;  // 64 threads
  int v[12];
  int s = 0;
#pragma unroll
  for (int z = 0; z < 12; ++z) {
    v[z] = deg[lane * 12 + z];
    s += v[z];
  }
  int inc = s;
#pragma unroll
  for (int d = 1; d < 64; d <<= 1) {
    int t = __shfl_up(inc, d, 64);
    if (lane >= d) inc += t;
  }
  int run = inc - s;
#pragma unroll
  for (int z = 0; z < 12; ++z) {
    run += v[z];
    offs[lane * 12 + z + 1] = run;
  }
  if (lane == 0) offs[0] = 0;
}

// ---------------------------------------------------------------------------
// Assign CSR slots to WINNING edges.
// ---------------------------------------------------------------------------
__global__ __launch_bounds__(256) void scatter_pos(
    const int* __restrict__ ei, const int* __restrict__ winner,
    const int* __restrict__ offs, int* __restrict__ curs,
    int* __restrict__ jlist, int* __restrict__ epos) {
  const int e = blockIdx.x * 256 + threadIdx.x;
  if (e >= E) return;
  const int s = ei[e];
  const int d = ei[E + e];
  if (winner[(size_t)s * N + d] != e) { epos[e] = -1; return; }
  const int pos = offs[d] + atomicAdd(&curs[d], 1);
  jlist[pos] = s;
  epos[e] = pos;
}

// ---------------------------------------------------------------------------
// Edge MLP: 20 -> 32 -> 32 -> 32 -> 64, winners only, CSR-ordered output.
// ---------------------------------------------------------------------------
__global__ __launch_bounds__(256, 2) void edge_mlp(
    const float* __restrict__ feat, const int* __restrict__ ei,
    const float* __restrict__ ea, const int* __restrict__ epos,
    const float* __restrict__ w0, const float* __restrict__ b0,
    const float* __restrict__ w1, const float* __restrict__ b1,
    const float* __restrict__ w2, const float* __restrict__ b2,
    const float* __restrict__ w3, const float* __restrict__ b3,
    float* __restrict__ Mlist) {
  const int e = blockIdx.x * 256 + threadIdx.x;
  if (e >= E) return;
  const int pos = epos[e];
  if (pos < 0) return;
  const int s = ei[e];
  const int d = ei[E + e];

  float x[20];
  {
    float4 t = *(const float4*)(ea + (size_t)e * 4);
    x[0] = t.x; x[1] = t.y; x[2] = t.z; x[3] = t.w;
    float4 f0 = *(const float4*)(feat + (size_t)s * 8);
    float4 f1 = *(const float4*)(feat + (size_t)s * 8 + 4);
    x[4] = f0.x; x[5] = f0.y; x[6] = f0.z; x[7] = f0.w;
    x[8] = f1.x; x[9] = f1.y; x[10] = f1.z; x[11] = f1.w;
    float4 g0 = *(const float4*)(feat + (size_t)d * 8);
    float4 g1 = *(const float4*)(feat + (size_t)d * 8 + 4);
    x[12] = g0.x; x[13] = g0.y; x[14] = g0.z; x[15] = g0.w;
    x[16] = g1.x; x[17] = g1.y; x[18] = g1.z; x[19] = g1.w;
  }

  float h[32];
#pragma unroll
  for (int o = 0; o < 32; ++o) {
    float acc = b0[o];
#pragma unroll
    for (int c = 0; c < 20; ++c) acc = fmaf(w0[o * 20 + c], x[c], acc);
    h[o] = fmaxf(acc, 0.f);
  }

  float g[32];
#pragma unroll
  for (int o = 0; o < 32; ++o) {
    float acc = b1[o];
#pragma unroll
    for (int c = 0; c < 32; ++c) acc = fmaf(w1[o * 32 + c], h[c], acc);
    g[o] = fmaxf(acc, 0.f);
  }
  float h2[32];
#pragma unroll
  for (int o = 0; o < 32; ++o) {
    float acc = b2[o];
#pragma unroll
    for (int c = 0; c < 32; ++c) acc = fmaf(w2[o * 32 + c], g[c], acc);
    h2[o] = fmaxf(acc, 0.f);
  }

  float* erow = Mlist + (size_t)pos * 64;
#pragma unroll
  for (int o4 = 0; o4 < 16; ++o4) {
    float r[4];
#pragma unroll
    for (int q = 0; q < 4; ++q) {
      const int o = o4 * 4 + q;
      float acc = b3[o];
#pragma unroll
      for (int c = 0; c < 32; ++c) acc = fmaf(w3[o * 32 + c], h2[c], acc);
      r[q] = acc;
    }
    *(float4*)(erow + o4 * 4) = make_float4(r[0], r[1], r[2], r[3]);
  }
}

// ---------------------------------------------------------------------------
// Walk contraction v5 — LDS-staged M stream (unchanged from round 5).
// ---------------------------------------------------------------------------
__device__ __forceinline__ void gload_lds16(const float* g, float* l) {
  __builtin_amdgcn_global_load_lds(
      (const __attribute__((address_space(1))) unsigned int*)g,
      (__attribute__((address_space(3))) unsigned int*)l, 16, 0, 0);
}

__global__ __launch_bounds__(128) void contract5(
    const float* __restrict__ mtrT, const float* __restrict__ Mlist,
    const int* __restrict__ jlist, const int* __restrict__ offs,
    const int* __restrict__ wcnt, float* __restrict__ WT) {
  __shared__ __align__(16) float Ms[2][CHF];

  const int b = blockIdx.x;
  const int g = (b & 7) * 576 + (b >> 3);  // XCD-chunked
  const int t = g / 768;
  const int k = g % 768;
  const int tid = threadIdx.x;
  const int lane = tid & 63;
  const int i = t * 128 + tid;

  const int base = offs[k];
  const int cnt = wcnt[k];
  const int nch = (cnt + CH - 1) / CH;

  float acc[8];
#pragma unroll
  for (int q = 0; q < 8; ++q) acc[q] = 0.f;

#define STAGE(ch_)                                                          \
  do {                                                                      \
    const int _c = (ch_);                                                   \
    if (_c * CH + (tid >> 4) < cnt) {                                       \
      const float* _g = Mlist + ((size_t)(base + _c * CH) * 64) + tid * 4;  \
      float* _l = &Ms[_c & 1][(tid >> 6) * 256];                            \
      gload_lds16(_g, _l);                                                  \
    }                                                                       \
  } while (0)

  if (nch > 0) STAGE(0);
  __syncthreads();

  int jv = 0;
#pragma unroll 1
  for (int ch = 0; ch < nch; ++ch) {
    if ((ch & 7) == 0) {
      const int o = ch * CH + lane;
      jv = (o < cnt) ? jlist[base + o] : 0;
    }
    if (ch + 1 < nch) STAGE(ch + 1);

    const float* Mb = &Ms[ch & 1][0];
    const int lim = min(CH, cnt - ch * CH);
#pragma unroll 2
    for (int q = 0; q < lim; ++q) {
      const int xx = ch * CH + q;
      const int j = __builtin_amdgcn_readlane(jv, xx & 63);

      const float* P = mtrT + ((size_t)j * N + i) * 8;
      float4 a = ((const float4*)P)[0];
      float4 bb = ((const float4*)P)[1];
      float v[8] = {a.x, a.y, a.z, a.w, bb.x, bb.y, bb.z, bb.w};

#pragma unroll
      for (int c = 0; c < 8; ++c) {
        float4 m0 = *(const float4*)&Mb[q * 64 + c * 8];
        float4 m1 = *(const float4*)&Mb[q * 64 + c * 8 + 4];
        acc[0] = fmaf(v[c], m0.x, acc[0]);
        acc[1] = fmaf(v[c], m0.y, acc[1]);
        acc[2] = fmaf(v[c], m0.z, acc[2]);
        acc[3] = fmaf(v[c], m0.w, acc[3]);
        acc[4] = fmaf(v[c], m1.x, acc[4]);
        acc[5] = fmaf(v[c], m1.y, acc[5]);
        acc[6] = fmaf(v[c], m1.z, acc[6]);
        acc[7] = fmaf(v[c], m1.w, acc[7]);
      }
    }
    __syncthreads();
  }
#undef STAGE

  float* dst = WT + ((size_t)k * N + i) * 8;
  *(float4*)(dst + 0) = make_float4(acc[0] * 0.125f, acc[1] * 0.125f,
                                    acc[2] * 0.125f, acc[3] * 0.125f);
  *(float4*)(dst + 4) = make_float4(acc[4] * 0.125f, acc[5] * 0.125f,
                                    acc[6] * 0.125f, acc[7] * 0.125f);
}

// ---------------------------------------------------------------------------
// Output MLP via MFMA (bf16 in, f32 accum).
// Rows = (i, k): x[32ch] = [WT[k][i](8), WT[i][k](8), feat[k](8), feat[i](8)],
// eye handled as a post-MFMA diagonal fixup (+w0[m][32] when k==i).
// Layers: 32->32->32->8 chained 16x16x32 MFMAs; D-frag == next B-frag slot
// labeling (two K=16 halves), so inter-layer = relu + cvt_pk only.
// Block = (i, 256-k slab); wave = 64 rows in 4 groups of 16. No LDS.
// ---------------------------------------------------------------------------
__device__ __forceinline__ unsigned pk2(float lo, float hi) {
  unsigned r;
  asm("v_cvt_pk_bf16_f32 %0, %1, %2" : "=v"(r) : "v"(lo), "v"(hi));
  return r;
}

union FragU {
  unsigned u[4];
  bf16x8 s;
};

__device__ __forceinline__ bf16x8 pack_frag(float4 a, float4 b) {
  FragU f;
  f.u[0] = pk2(a.x, a.y);
  f.u[1] = pk2(a.z, a.w);
  f.u[2] = pk2(b.x, b.y);
  f.u[3] = pk2(b.z, b.w);
  return f.s;
}

__device__ __forceinline__ bf16x8 relu_pack(f32x4 d1, f32x4 d2) {
  FragU f;
  f.u[0] = pk2(fmaxf(d1[0], 0.f), fmaxf(d1[1], 0.f));
  f.u[1] = pk2(fmaxf(d1[2], 0.f), fmaxf(d1[3], 0.f));
  f.u[2] = pk2(fmaxf(d2[0], 0.f), fmaxf(d2[1], 0.f));
  f.u[3] = pk2(fmaxf(d2[2], 0.f), fmaxf(d2[3], 0.f));
  return f.s;
}

__device__ __forceinline__ f32x4 ld4(const float* p) {
  float4 v = *(const float4*)p;
  f32x4 r;
  r[0] = v.x; r[1] = v.y; r[2] = v.z; r[3] = v.w;
  return r;
}

__global__ __launch_bounds__(256, 2) void out_mlp_mfma(
    const float* __restrict__ mtr, const float* __restrict__ WT,
    const float* __restrict__ feat,
    const float* __restrict__ w0, const float* __restrict__ b0,
    const float* __restrict__ w1, const float* __restrict__ b1,
    const float* __restrict__ w2, const float* __restrict__ b2,
    const float* __restrict__ w3, const float* __restrict__ b3,
    float* __restrict__ out) {
  const int i = blockIdx.y;
  const int k0 = blockIdx.x * 256;
  const int w = threadIdx.x >> 6;          // wave 0..3
  const int col = threadIdx.x & 15;        // row-in-group / A-row m
  const int hi = (threadIdx.x >> 4) & 3;   // k-half-group 0..3

  // ---- A-frags (weights), slot labeling: j0-3 -> k=hi*4+j, j4-7 -> 16+hi*4+j
  bf16x8 a0lo, a0hi, a1lo, a1hi, a2lo, a2hi, a3;
  {
    // w0: stride 33 (unaligned) -> scalar loads
    const float* p = w0 + col * 33;
    float4 xa = make_float4(p[hi * 4], p[hi * 4 + 1], p[hi * 4 + 2], p[hi * 4 + 3]);
    float4 xb = make_float4(p[16 + hi * 4], p[16 + hi * 4 + 1],
                            p[16 + hi * 4 + 2], p[16 + hi * 4 + 3]);
    a0lo = pack_frag(xa, xb);
    const float* q = w0 + (col + 16) * 33;
    float4 ya = make_float4(q[hi * 4], q[hi * 4 + 1], q[hi * 4 + 2], q[hi * 4 + 3]);
    float4 yb = make_float4(q[16 + hi * 4], q[16 + hi * 4 + 1],
                            q[16 + hi * 4 + 2], q[16 + hi * 4 + 3]);
    a0hi = pack_frag(ya, yb);
  }
  a1lo = pack_frag(*(const float4*)(w1 + col * 32 + hi * 4),
                   *(const float4*)(w1 + col * 32 + 16 + hi * 4));
  a1hi = pack_frag(*(const float4*)(w1 + (col + 16) * 32 + hi * 4),
                   *(const float4*)(w1 + (col + 16) * 32 + 16 + hi * 4));
  a2lo = pack_frag(*(const float4*)(w2 + col * 32 + hi * 4),
                   *(const float4*)(w2 + col * 32 + 16 + hi * 4));
  a2hi = pack_frag(*(const float4*)(w2 + (col + 16) * 32 + hi * 4),
                   *(const float4*)(w2 + (col + 16) * 32 + 16 + hi * 4));
  if (col < 8) {
    a3 = pack_frag(*(const float4*)(w3 + col * 32 + hi * 4),
                   *(const float4*)(w3 + col * 32 + 16 + hi * 4));
  } else {
    FragU z; z.u[0] = z.u[1] = z.u[2] = z.u[3] = 0; a3 = z.s;
  }

  // ---- bias C-init frags (D m-map: hi*4+r / 16+hi*4+r) and diagonal fixups
  const f32x4 c1a = ld4(b0 + hi * 4), c1b = ld4(b0 + 16 + hi * 4);
  const f32x4 c2a = ld4(b1 + hi * 4), c2b = ld4(b1 + 16 + hi * 4);
  const f32x4 c3a = ld4(b2 + hi * 4), c3b = ld4(b2 + 16 + hi * 4);
  f32x4 c4;
  if (hi < 2) c4 = ld4(b3 + hi * 4);
  else { c4[0] = c4[1] = c4[2] = c4[3] = 0.f; }

  float dg1[4], dg2[4];
#pragma unroll
  for (int r = 0; r < 4; ++r) {
    dg1[r] = w0[(hi * 4 + r) * 33 + 32];
    dg2[r] = w0[(16 + hi * 4 + r) * 33 + 32];
  }

#pragma unroll 1
  for (int g = 0; g < 4; ++g) {
    const int krow = k0 + w * 64 + g * 16 + col;

    // ---- layer-0 input frag
    const float* pA = (hi < 2) ? (WT + ((size_t)krow * N + i) * 8 + (hi & 1) * 4)
                               : (WT + ((size_t)i * N + krow) * 8 + (hi & 1) * 4);
    const float* pB = (hi < 2) ? (feat + (size_t)krow * 8 + (hi & 1) * 4)
                               : (feat + (size_t)i * 8 + (hi & 1) * 4);
    bf16x8 bfr = pack_frag(*(const float4*)pA, *(const float4*)pB);

    // ---- layer 0
    f32x4 d1 = c1a, d2 = c1b;
    d1 = __builtin_amdgcn_mfma_f32_16x16x32_bf16(a0lo, bfr, d1, 0, 0, 0);
    d2 = __builtin_amdgcn_mfma_f32_16x16x32_bf16(a0hi, bfr, d2, 0, 0, 0);
    const float eye = (krow == i) ? 1.f : 0.f;
#pragma unroll
    for (int r = 0; r < 4; ++r) {
      d1[r] = fmaf(eye, dg1[r], d1[r]);
      d2[r] = fmaf(eye, dg2[r], d2[r]);
    }
    bfr = relu_pack(d1, d2);

    // ---- layer 1
    d1 = c2a; d2 = c2b;
    d1 = __builtin_amdgcn_mfma_f32_16x16x32_bf16(a1lo, bfr, d1, 0, 0, 0);
    d2 = __builtin_amdgcn_mfma_f32_16x16x32_bf16(a1hi, bfr, d2, 0, 0, 0);
    bfr = relu_pack(d1, d2);

    // ---- layer 2
    d1 = c3a; d2 = c3b;
    d1 = __builtin_amdgcn_mfma_f32_16x16x32_bf16(a2lo, bfr, d1, 0, 0, 0);
    d2 = __builtin_amdgcn_mfma_f32_16x16x32_bf16(a2hi, bfr, d2, 0, 0, 0);
    bfr = relu_pack(d1, d2);

    // ---- layer 3 (8 outputs; rows m>=8 of A are zero)
    f32x4 d3 = c4;
    d3 = __builtin_amdgcn_mfma_f32_16x16x32_bf16(a3, bfr, d3, 0, 0, 0);

    // ---- residual add + store (lanes hi<2 hold the 8 valid outputs)
    if (hi < 2) {
      const size_t idx = ((size_t)i * N + krow) * 8 + hi * 4;
      float4 m = *(const float4*)(mtr + idx);
      *(float4*)(out + idx) =
          make_float4(m.x + d3[0], m.y + d3[1], m.z + d3[2], m.w + d3[3]);
    }
  }
}

// ---------------------------------------------------------------------------
extern "C" void kernel_launch(void* const* d_in, const int* in_sizes, int n_in,
                              void* d_out, int out_size, void* d_ws,
                              size_t ws_size, hipStream_t stream) {
  const float* mtr  = (const float*)d_in[0];
  const float* feat = (const float*)d_in[1];
  const int*   ei   = (const int*)d_in[2];
  const float* ea   = (const float*)d_in[3];
  const float* ew0 = (const float*)d_in[4];
  const float* eb0 = (const float*)d_in[5];
  const float* ew1 = (const float*)d_in[6];
  const float* eb1 = (const float*)d_in[7];
  const float* ew2 = (const float*)d_in[8];
  const float* eb2 = (const float*)d_in[9];
  const float* ew3 = (const float*)d_in[10];
  const float* eb3 = (const float*)d_in[11];
  const float* ow0 = (const float*)d_in[12];
  const float* ob0 = (const float*)d_in[13];
  const float* ow1 = (const float*)d_in[14];
  const float* ob1 = (const float*)d_in[15];
  const float* ow2 = (const float*)d_in[16];
  const float* ob2 = (const float*)d_in[17];
  const float* ow3 = (const float*)d_in[18];
  const float* ob3 = (const float*)d_in[19];
  float* out = (float*)d_out;

  char* ws = (char*)d_ws;
  float* Mlist = (float*)ws; ws += (size_t)(E + 16) * 64 * 4;  // 6.3 MB
  float* mtrT  = (float*)ws; ws += (size_t)N * N * 8 * 4;      // 18.87 MB
  float* WT    = (float*)ws; ws += (size_t)N * N * 8 * 4;      // 18.87 MB
  int* winner  = (int*)ws;   ws += (size_t)N * N * 4;          // 2.36 MB
  int* deg     = (int*)ws;   ws += 1024 * 4;
  int* offs    = (int*)ws;   ws += 1024 * 4;
  int* curs    = (int*)ws;   ws += 1024 * 4;
  int* jlist   = (int*)ws;   ws += (size_t)E * 4;
  int* epos    = (int*)ws;   ws += (size_t)E * 4;

  init_ws<<<576, 256, 0, stream>>>((int4*)winner, deg, curs);
  edge_prep<<<E / 256, 256, 0, stream>>>(ei, winner, deg);
  scan_offs<<<1, 64, 0, stream>>>(deg, offs);
  scatter_pos<<<E / 256, 256, 0, stream>>>(ei, winner, offs, curs, jlist, epos);
  transpose_mtr<<<dim3(48, 48), 256, 0, stream>>>(mtr, mtrT);
  edge_mlp<<<E / 256, 256, 0, stream>>>(feat, ei, ea, epos, ew0, eb0, ew1, eb1,
                                        ew2, eb2, ew3, eb3, Mlist);
  contract5<<<4608, 128, 0, stream>>>(mtrT, Mlist, jlist, offs, curs, WT);
  out_mlp_mfma<<<dim3(3, N), 256, 0, stream>>>(mtr, WT, feat, ow0, ob0, ow1,
                                               ob1, ow2, ob2, ow3, ob3, out);
}

// Round 8
// 127.165 us; speedup vs baseline: 1.6511x; 1.3329x over previous
//
#include <hip/hip_runtime.h>

#define N 768
#define E 24576
#define CH 8             // edges per staged LDS chunk
#define CHF (CH * 64)    // floats per chunk (512 = 2 KB)

typedef __attribute__((ext_vector_type(8))) short bf16x8;
typedef __attribute__((ext_vector_type(4))) float f32x4;

// ---------------------------------------------------------------------------
// Workspace init: winner = -1, deg/curs = 0.
// ---------------------------------------------------------------------------
__global__ __launch_bounds__(256) void init_ws(int4* __restrict__ winner4,
                                               int* __restrict__ deg,
                                               int* __restrict__ curs) {
  const int t = blockIdx.x * 256 + threadIdx.x;  // 576*256 = N*N/4
  winner4[t] = make_int4(-1, -1, -1, -1);
  if (t < 1024) { deg[t] = 0; curs[t] = 0; }
}

// ---------------------------------------------------------------------------
// Transpose mtr [i][j][8] -> mtrT [j][i][8].
// ---------------------------------------------------------------------------
__global__ __launch_bounds__(256) void transpose_mtr(
    const float* __restrict__ mtr, float* __restrict__ mtrT) {
  __shared__ float lds[16][16 * 8 + 4];
  const int r = threadIdx.x >> 4;
  const int c = threadIdx.x & 15;
  const size_t i0 = (size_t)blockIdx.y * 16;
  const size_t j0 = (size_t)blockIdx.x * 16;

  const float4* src = (const float4*)(mtr + ((i0 + r) * N + (j0 + c)) * 8);
  float4 a = src[0], b = src[1];
  *(float4*)&lds[r][c * 8 + 0] = a;
  *(float4*)&lds[r][c * 8 + 4] = b;
  __syncthreads();
  float4* dst = (float4*)(mtrT + ((j0 + r) * N + (i0 + c)) * 8);
  dst[0] = *(float4*)&lds[c][r * 8 + 0];
  dst[1] = *(float4*)&lds[c][r * 8 + 4];
}

// ---------------------------------------------------------------------------
// Pre-pass: winner marking + dst-degree histogram.
// ---------------------------------------------------------------------------
__global__ __launch_bounds__(256) void edge_prep(
    const int* __restrict__ ei, int* __restrict__ winner,
    int* __restrict__ deg) {
  const int e = blockIdx.x * 256 + threadIdx.x;
  if (e >= E) return;
  const int s = ei[e];
  const int d = ei[E + e];
  atomicMax(&winner[(size_t)s * N + d], e);
  atomicAdd(&deg[d], 1);
}

// ---------------------------------------------------------------------------
// Exclusive scan of deg[0..768) -> offs[0..768]. One wave, 12 values/lane.
// ---------------------------------------------------------------------------
__global__ void scan_offs(const int* __restrict__ deg, int* __restrict__ offs) {
  const int lane = threadIdx.x;  // 64 threads
  int v[12];
  int s = 0;
#pragma unroll
  for (int z = 0; z < 12; ++z) {
    v[z] = deg[lane * 12 + z];
    s += v[z];
  }
  int inc = s;
#pragma unroll
  for (int d = 1; d < 64; d <<= 1) {
    int t = __shfl_up(inc, d, 64);
    if (lane >= d) inc += t;
  }
  int run = inc - s;
#pragma unroll
  for (int z = 0; z < 12; ++z) {
    run += v[z];
    offs[lane * 12 + z + 1] = run;
  }
  if (lane == 0) offs[0] = 0;
}

// ---------------------------------------------------------------------------
// Assign CSR slots to WINNING edges.
// ---------------------------------------------------------------------------
__global__ __launch_bounds__(256) void scatter_pos(
    const int* __restrict__ ei, const int* __restrict__ winner,
    const int* __restrict__ offs, int* __restrict__ curs,
    int* __restrict__ jlist, int* __restrict__ epos) {
  const int e = blockIdx.x * 256 + threadIdx.x;
  if (e >= E) return;
  const int s = ei[e];
  const int d = ei[E + e];
  if (winner[(size_t)s * N + d] != e) { epos[e] = -1; return; }
  const int pos = offs[d] + atomicAdd(&curs[d], 1);
  jlist[pos] = s;
  epos[e] = pos;
}

// ---------------------------------------------------------------------------
// MFMA helpers (slot labeling: j0-3 -> k = hi*4+j, j4-7 -> k = 16+hi*4+j;
// D m-map: rows hi*4+r. Validated on HW by out_mlp_mfma in round 7.)
// ---------------------------------------------------------------------------
__device__ __forceinline__ unsigned pk2(float lo, float hi) {
  unsigned r;
  asm("v_cvt_pk_bf16_f32 %0, %1, %2" : "=v"(r) : "v"(lo), "v"(hi));
  return r;
}

union FragU {
  unsigned u[4];
  bf16x8 s;
};

__device__ __forceinline__ bf16x8 pack_frag(float4 a, float4 b) {
  FragU f;
  f.u[0] = pk2(a.x, a.y);
  f.u[1] = pk2(a.z, a.w);
  f.u[2] = pk2(b.x, b.y);
  f.u[3] = pk2(b.z, b.w);
  return f.s;
}

__device__ __forceinline__ bf16x8 relu_pack(f32x4 d1, f32x4 d2) {
  FragU f;
  f.u[0] = pk2(fmaxf(d1[0], 0.f), fmaxf(d1[1], 0.f));
  f.u[1] = pk2(fmaxf(d1[2], 0.f), fmaxf(d1[3], 0.f));
  f.u[2] = pk2(fmaxf(d2[0], 0.f), fmaxf(d2[1], 0.f));
  f.u[3] = pk2(fmaxf(d2[2], 0.f), fmaxf(d2[3], 0.f));
  return f.s;
}

__device__ __forceinline__ f32x4 ld4(const float* p) {
  float4 v = *(const float4*)p;
  f32x4 r;
  r[0] = v.x; r[1] = v.y; r[2] = v.z; r[3] = v.w;
  return r;
}

// ---------------------------------------------------------------------------
// Edge MLP via MFMA: [16 edges/wave] x (20(+pad12) -> 32 -> 32 -> 32 -> 64).
// Input channels: [ea(4), feat[src](8), feat[dst](8), 0...].
// 10 MFMAs per wave; winners store into CSR order (losers computed, skipped).
// One wave per block; 1536 blocks.
// ---------------------------------------------------------------------------
__global__ __launch_bounds__(64) void edge_mlp_mfma(
    const float* __restrict__ feat, const int* __restrict__ ei,
    const float* __restrict__ ea, const int* __restrict__ epos,
    const float* __restrict__ w0, const float* __restrict__ b0,
    const float* __restrict__ w1, const float* __restrict__ b1,
    const float* __restrict__ w2, const float* __restrict__ b2,
    const float* __restrict__ w3, const float* __restrict__ b3,
    float* __restrict__ Mlist) {
  const int col = threadIdx.x & 15;        // edge-in-tile / A-row m
  const int hi = (threadIdx.x >> 4) & 3;   // k-half-group
  const int e = blockIdx.x * 16 + col;

  const float4 z4 = make_float4(0.f, 0.f, 0.f, 0.f);

  // ---- input B-frag gather ----
  const int s = ei[e];
  const int d = ei[E + e];
  const int pos = epos[e];
  const float* pa = (hi == 0) ? (ea + (size_t)e * 4)
                  : (hi == 1) ? (feat + (size_t)s * 8)
                  : (hi == 2) ? (feat + (size_t)s * 8 + 4)
                              : (feat + (size_t)d * 8);
  float4 va = *(const float4*)pa;
  float4 vb = (hi == 0) ? *(const float4*)(feat + (size_t)d * 8 + 4) : z4;
  bf16x8 bfr = pack_frag(va, vb);

  // ---- weight A-frags ----
  bf16x8 a0lo, a0hi, a1lo, a1hi, a2lo, a2hi, a3f[4];
  {
    const float* p = w0 + col * 20;        // row `col`, stride 20 (16B-aligned)
    float4 xa = *(const float4*)(p + hi * 4);
    float4 xb = (hi == 0) ? *(const float4*)(p + 16) : z4;
    a0lo = pack_frag(xa, xb);
    const float* q = w0 + (col + 16) * 20;
    float4 ya = *(const float4*)(q + hi * 4);
    float4 yb = (hi == 0) ? *(const float4*)(q + 16) : z4;
    a0hi = pack_frag(ya, yb);
  }
  a1lo = pack_frag(*(const float4*)(w1 + col * 32 + hi * 4),
                   *(const float4*)(w1 + col * 32 + 16 + hi * 4));
  a1hi = pack_frag(*(const float4*)(w1 + (col + 16) * 32 + hi * 4),
                   *(const float4*)(w1 + (col + 16) * 32 + 16 + hi * 4));
  a2lo = pack_frag(*(const float4*)(w2 + col * 32 + hi * 4),
                   *(const float4*)(w2 + col * 32 + 16 + hi * 4));
  a2hi = pack_frag(*(const float4*)(w2 + (col + 16) * 32 + hi * 4),
                   *(const float4*)(w2 + (col + 16) * 32 + 16 + hi * 4));
#pragma unroll
  for (int q = 0; q < 4; ++q) {
    const float* p = w3 + (size_t)(q * 16 + col) * 32;
    a3f[q] = pack_frag(*(const float4*)(p + hi * 4),
                       *(const float4*)(p + 16 + hi * 4));
  }

  // ---- layer 0 (bias C-init) ----
  f32x4 d1 = ld4(b0 + hi * 4), d2 = ld4(b0 + 16 + hi * 4);
  d1 = __builtin_amdgcn_mfma_f32_16x16x32_bf16(a0lo, bfr, d1, 0, 0, 0);
  d2 = __builtin_amdgcn_mfma_f32_16x16x32_bf16(a0hi, bfr, d2, 0, 0, 0);
  bfr = relu_pack(d1, d2);

  // ---- layer 1 ----
  d1 = ld4(b1 + hi * 4); d2 = ld4(b1 + 16 + hi * 4);
  d1 = __builtin_amdgcn_mfma_f32_16x16x32_bf16(a1lo, bfr, d1, 0, 0, 0);
  d2 = __builtin_amdgcn_mfma_f32_16x16x32_bf16(a1hi, bfr, d2, 0, 0, 0);
  bfr = relu_pack(d1, d2);

  // ---- layer 2 ----
  d1 = ld4(b2 + hi * 4); d2 = ld4(b2 + 16 + hi * 4);
  d1 = __builtin_amdgcn_mfma_f32_16x16x32_bf16(a2lo, bfr, d1, 0, 0, 0);
  d2 = __builtin_amdgcn_mfma_f32_16x16x32_bf16(a2hi, bfr, d2, 0, 0, 0);
  bfr = relu_pack(d1, d2);

  // ---- layer 3: 64 outputs = 4 m-block MFMAs; store winners to CSR slot ----
#pragma unroll
  for (int q = 0; q < 4; ++q) {
    f32x4 d3 = ld4(b3 + q * 16 + hi * 4);
    d3 = __builtin_amdgcn_mfma_f32_16x16x32_bf16(a3f[q], bfr, d3, 0, 0, 0);
    if (pos >= 0) {
      *(float4*)(Mlist + (size_t)pos * 64 + q * 16 + hi * 4) =
          make_float4(d3[0], d3[1], d3[2], d3[3]);
    }
  }
}

// ---------------------------------------------------------------------------
// Walk contraction v5 — LDS-staged M stream (unchanged).
// ---------------------------------------------------------------------------
__device__ __forceinline__ void gload_lds16(const float* g, float* l) {
  __builtin_amdgcn_global_load_lds(
      (const __attribute__((address_space(1))) unsigned int*)g,
      (__attribute__((address_space(3))) unsigned int*)l, 16, 0, 0);
}

__global__ __launch_bounds__(128) void contract5(
    const float* __restrict__ mtrT, const float* __restrict__ Mlist,
    const int* __restrict__ jlist, const int* __restrict__ offs,
    const int* __restrict__ wcnt, float* __restrict__ WT) {
  __shared__ __align__(16) float Ms[2][CHF];

  const int b = blockIdx.x;
  const int g = (b & 7) * 576 + (b >> 3);  // XCD-chunked
  const int t = g / 768;
  const int k = g % 768;
  const int tid = threadIdx.x;
  const int lane = tid & 63;
  const int i = t * 128 + tid;

  const int base = offs[k];
  const int cnt = wcnt[k];
  const int nch = (cnt + CH - 1) / CH;

  float acc[8];
#pragma unroll
  for (int q = 0; q < 8; ++q) acc[q] = 0.f;

#define STAGE(ch_)                                                          \
  do {                                                                      \
    const int _c = (ch_);                                                   \
    if (_c * CH + (tid >> 4) < cnt) {                                       \
      const float* _g = Mlist + ((size_t)(base + _c * CH) * 64) + tid * 4;  \
      float* _l = &Ms[_c & 1][(tid >> 6) * 256];                            \
      gload_lds16(_g, _l);                                                  \
    }                                                                       \
  } while (0)

  if (nch > 0) STAGE(0);
  __syncthreads();

  int jv = 0;
#pragma unroll 1
  for (int ch = 0; ch < nch; ++ch) {
    if ((ch & 7) == 0) {
      const int o = ch * CH + lane;
      jv = (o < cnt) ? jlist[base + o] : 0;
    }
    if (ch + 1 < nch) STAGE(ch + 1);

    const float* Mb = &Ms[ch & 1][0];
    const int lim = min(CH, cnt - ch * CH);
#pragma unroll 2
    for (int q = 0; q < lim; ++q) {
      const int xx = ch * CH + q;
      const int j = __builtin_amdgcn_readlane(jv, xx & 63);

      const float* P = mtrT + ((size_t)j * N + i) * 8;
      float4 a = ((const float4*)P)[0];
      float4 bb = ((const float4*)P)[1];
      float v[8] = {a.x, a.y, a.z, a.w, bb.x, bb.y, bb.z, bb.w};

#pragma unroll
      for (int c = 0; c < 8; ++c) {
        float4 m0 = *(const float4*)&Mb[q * 64 + c * 8];
        float4 m1 = *(const float4*)&Mb[q * 64 + c * 8 + 4];
        acc[0] = fmaf(v[c], m0.x, acc[0]);
        acc[1] = fmaf(v[c], m0.y, acc[1]);
        acc[2] = fmaf(v[c], m0.z, acc[2]);
        acc[3] = fmaf(v[c], m0.w, acc[3]);
        acc[4] = fmaf(v[c], m1.x, acc[4]);
        acc[5] = fmaf(v[c], m1.y, acc[5]);
        acc[6] = fmaf(v[c], m1.z, acc[6]);
        acc[7] = fmaf(v[c], m1.w, acc[7]);
      }
    }
    __syncthreads();
  }
#undef STAGE

  float* dst = WT + ((size_t)k * N + i) * 8;
  *(float4*)(dst + 0) = make_float4(acc[0] * 0.125f, acc[1] * 0.125f,
                                    acc[2] * 0.125f, acc[3] * 0.125f);
  *(float4*)(dst + 4) = make_float4(acc[4] * 0.125f, acc[5] * 0.125f,
                                    acc[6] * 0.125f, acc[7] * 0.125f);
}

// ---------------------------------------------------------------------------
// Output MLP via MFMA (unchanged from round 7).
// ---------------------------------------------------------------------------
__global__ __launch_bounds__(256, 2) void out_mlp_mfma(
    const float* __restrict__ mtr, const float* __restrict__ WT,
    const float* __restrict__ feat,
    const float* __restrict__ w0, const float* __restrict__ b0,
    const float* __restrict__ w1, const float* __restrict__ b1,
    const float* __restrict__ w2, const float* __restrict__ b2,
    const float* __restrict__ w3, const float* __restrict__ b3,
    float* __restrict__ out) {
  const int i = blockIdx.y;
  const int k0 = blockIdx.x * 256;
  const int w = threadIdx.x >> 6;          // wave 0..3
  const int col = threadIdx.x & 15;        // row-in-group / A-row m
  const int hi = (threadIdx.x >> 4) & 3;   // k-half-group 0..3

  bf16x8 a0lo, a0hi, a1lo, a1hi, a2lo, a2hi, a3;
  {
    const float* p = w0 + col * 33;
    float4 xa = make_float4(p[hi * 4], p[hi * 4 + 1], p[hi * 4 + 2], p[hi * 4 + 3]);
    float4 xb = make_float4(p[16 + hi * 4], p[16 + hi * 4 + 1],
                            p[16 + hi * 4 + 2], p[16 + hi * 4 + 3]);
    a0lo = pack_frag(xa, xb);
    const float* q = w0 + (col + 16) * 33;
    float4 ya = make_float4(q[hi * 4], q[hi * 4 + 1], q[hi * 4 + 2], q[hi * 4 + 3]);
    float4 yb = make_float4(q[16 + hi * 4], q[16 + hi * 4 + 1],
                            q[16 + hi * 4 + 2], q[16 + hi * 4 + 3]);
    a0hi = pack_frag(ya, yb);
  }
  a1lo = pack_frag(*(const float4*)(w1 + col * 32 + hi * 4),
                   *(const float4*)(w1 + col * 32 + 16 + hi * 4));
  a1hi = pack_frag(*(const float4*)(w1 + (col + 16) * 32 + hi * 4),
                   *(const float4*)(w1 + (col + 16) * 32 + 16 + hi * 4));
  a2lo = pack_frag(*(const float4*)(w2 + col * 32 + hi * 4),
                   *(const float4*)(w2 + col * 32 + 16 + hi * 4));
  a2hi = pack_frag(*(const float4*)(w2 + (col + 16) * 32 + hi * 4),
                   *(const float4*)(w2 + (col + 16) * 32 + 16 + hi * 4));
  if (col < 8) {
    a3 = pack_frag(*(const float4*)(w3 + col * 32 + hi * 4),
                   *(const float4*)(w3 + col * 32 + 16 + hi * 4));
  } else {
    FragU z; z.u[0] = z.u[1] = z.u[2] = z.u[3] = 0; a3 = z.s;
  }

  const f32x4 c1a = ld4(b0 + hi * 4), c1b = ld4(b0 + 16 + hi * 4);
  const f32x4 c2a = ld4(b1 + hi * 4), c2b = ld4(b1 + 16 + hi * 4);
  const f32x4 c3a = ld4(b2 + hi * 4), c3b = ld4(b2 + 16 + hi * 4);
  f32x4 c4;
  if (hi < 2) c4 = ld4(b3 + hi * 4);
  else { c4[0] = c4[1] = c4[2] = c4[3] = 0.f; }

  float dg1[4], dg2[4];
#pragma unroll
  for (int r = 0; r < 4; ++r) {
    dg1[r] = w0[(hi * 4 + r) * 33 + 32];
    dg2[r] = w0[(16 + hi * 4 + r) * 33 + 32];
  }

#pragma unroll 1
  for (int g = 0; g < 4; ++g) {
    const int krow = k0 + w * 64 + g * 16 + col;

    const float* pA = (hi < 2) ? (WT + ((size_t)krow * N + i) * 8 + (hi & 1) * 4)
                               : (WT + ((size_t)i * N + krow) * 8 + (hi & 1) * 4);
    const float* pB = (hi < 2) ? (feat + (size_t)krow * 8 + (hi & 1) * 4)
                               : (feat + (size_t)i * 8 + (hi & 1) * 4);
    bf16x8 bfr = pack_frag(*(const float4*)pA, *(const float4*)pB);

    f32x4 d1 = c1a, d2 = c1b;
    d1 = __builtin_amdgcn_mfma_f32_16x16x32_bf16(a0lo, bfr, d1, 0, 0, 0);
    d2 = __builtin_amdgcn_mfma_f32_16x16x32_bf16(a0hi, bfr, d2, 0, 0, 0);
    const float eye = (krow == i) ? 1.f : 0.f;
#pragma unroll
    for (int r = 0; r < 4; ++r) {
      d1[r] = fmaf(eye, dg1[r], d1[r]);
      d2[r] = fmaf(eye, dg2[r], d2[r]);
    }
    bfr = relu_pack(d1, d2);

    d1 = c2a; d2 = c2b;
    d1 = __builtin_amdgcn_mfma_f32_16x16x32_bf16(a1lo, bfr, d1, 0, 0, 0);
    d2 = __builtin_amdgcn_mfma_f32_16x16x32_bf16(a1hi, bfr, d2, 0, 0, 0);
    bfr = relu_pack(d1, d2);

    d1 = c3a; d2 = c3b;
    d1 = __builtin_amdgcn_mfma_f32_16x16x32_bf16(a2lo, bfr, d1, 0, 0, 0);
    d2 = __builtin_amdgcn_mfma_f32_16x16x32_bf16(a2hi, bfr, d2, 0, 0, 0);
    bfr = relu_pack(d1, d2);

    f32x4 d3 = c4;
    d3 = __builtin_amdgcn_mfma_f32_16x16x32_bf16(a3, bfr, d3, 0, 0, 0);

    if (hi < 2) {
      const size_t idx = ((size_t)i * N + krow) * 8 + hi * 4;
      float4 m = *(const float4*)(mtr + idx);
      *(float4*)(out + idx) =
          make_float4(m.x + d3[0], m.y + d3[1], m.z + d3[2], m.w + d3[3]);
    }
  }
}

// ---------------------------------------------------------------------------
extern "C" void kernel_launch(void* const* d_in, const int* in_sizes, int n_in,
                              void* d_out, int out_size, void* d_ws,
                              size_t ws_size, hipStream_t stream) {
  const float* mtr  = (const float*)d_in[0];
  const float* feat = (const float*)d_in[1];
  const int*   ei   = (const int*)d_in[2];
  const float* ea   = (const float*)d_in[3];
  const float* ew0 = (const float*)d_in[4];
  const float* eb0 = (const float*)d_in[5];
  const float* ew1 = (const float*)d_in[6];
  const float* eb1 = (const float*)d_in[7];
  const float* ew2 = (const float*)d_in[8];
  const float* eb2 = (const float*)d_in[9];
  const float* ew3 = (const float*)d_in[10];
  const float* eb3 = (const float*)d_in[11];
  const float* ow0 = (const float*)d_in[12];
  const float* ob0 = (const float*)d_in[13];
  const float* ow1 = (const float*)d_in[14];
  const float* ob1 = (const float*)d_in[15];
  const float* ow2 = (const float*)d_in[16];
  const float* ob2 = (const float*)d_in[17];
  const float* ow3 = (const float*)d_in[18];
  const float* ob3 = (const float*)d_in[19];
  float* out = (float*)d_out;

  char* ws = (char*)d_ws;
  float* Mlist = (float*)ws; ws += (size_t)(E + 16) * 64 * 4;  // 6.3 MB
  float* mtrT  = (float*)ws; ws += (size_t)N * N * 8 * 4;      // 18.87 MB
  float* WT    = (float*)ws; ws += (size_t)N * N * 8 * 4;      // 18.87 MB
  int* winner  = (int*)ws;   ws += (size_t)N * N * 4;          // 2.36 MB
  int* deg     = (int*)ws;   ws += 1024 * 4;
  int* offs    = (int*)ws;   ws += 1024 * 4;
  int* curs    = (int*)ws;   ws += 1024 * 4;
  int* jlist   = (int*)ws;   ws += (size_t)E * 4;
  int* epos    = (int*)ws;   ws += (size_t)E * 4;

  init_ws<<<576, 256, 0, stream>>>((int4*)winner, deg, curs);
  edge_prep<<<E / 256, 256, 0, stream>>>(ei, winner, deg);
  scan_offs<<<1, 64, 0, stream>>>(deg, offs);
  scatter_pos<<<E / 256, 256, 0, stream>>>(ei, winner, offs, curs, jlist, epos);
  transpose_mtr<<<dim3(48, 48), 256, 0, stream>>>(mtr, mtrT);
  edge_mlp_mfma<<<E / 16, 64, 0, stream>>>(feat, ei, ea, epos, ew0, eb0, ew1,
                                           eb1, ew2, eb2, ew3, eb3, Mlist);
  contract5<<<4608, 128, 0, stream>>>(mtrT, Mlist, jlist, offs, curs, WT);
  out_mlp_mfma<<<dim3(3, N), 256, 0, stream>>>(mtr, WT, feat, ow0, ob0, ow1,
                                               ob1, ow2, ob2, ow3, ob3, out);
}

// Round 9
// 105.556 us; speedup vs baseline: 1.9891x; 1.2047x over previous
//
#include <hip/hip_runtime.h>

#define N 768
#define E 24576
#define NPAD_SLOTS (E + 3 * 768)      // 26880 max padded CSR slots
#define NGROUPS (NPAD_SLOTS / 4)      // 6720 K=32 groups
#define MLIST_SLOTS (NPAD_SLOTS + 16) // 26896 (alloc pad)

typedef __attribute__((ext_vector_type(8))) short bf16x8;
typedef __attribute__((ext_vector_type(4))) float f32x4;

// ---------------------------------------------------------------------------
// MFMA helpers — slot convention validated on HW (rounds 7/8):
// A/B lane (col, hi): slots j0-3 = k=hi*4+j, j4-7 = k=16+hi*4+j (lo 16b = even)
// C/D lane (col, hi): D[row = hi*4+r][col].
// ---------------------------------------------------------------------------
__device__ __forceinline__ unsigned pk2(float lo, float hi) {
  unsigned r;
  asm("v_cvt_pk_bf16_f32 %0, %1, %2" : "=v"(r) : "v"(lo), "v"(hi));
  return r;
}

union FragU {
  unsigned u[4];
  bf16x8 s;
};

__device__ __forceinline__ bf16x8 pack_frag(float4 a, float4 b) {
  FragU f;
  f.u[0] = pk2(a.x, a.y);
  f.u[1] = pk2(a.z, a.w);
  f.u[2] = pk2(b.x, b.y);
  f.u[3] = pk2(b.z, b.w);
  return f.s;
}

__device__ __forceinline__ bf16x8 relu_pack(f32x4 d1, f32x4 d2) {
  FragU f;
  f.u[0] = pk2(fmaxf(d1[0], 0.f), fmaxf(d1[1], 0.f));
  f.u[1] = pk2(fmaxf(d1[2], 0.f), fmaxf(d1[3], 0.f));
  f.u[2] = pk2(fmaxf(d2[0], 0.f), fmaxf(d2[1], 0.f));
  f.u[3] = pk2(fmaxf(d2[2], 0.f), fmaxf(d2[3], 0.f));
  return f.s;
}

__device__ __forceinline__ f32x4 ld4(const float* p) {
  float4 v = *(const float4*)p;
  f32x4 r;
  r[0] = v.x; r[1] = v.y; r[2] = v.z; r[3] = v.w;
  return r;
}

// ---------------------------------------------------------------------------
// Workspace init: winner=-1, Mlist=0 (pad slots must contribute 0),
// jlist=0 (pad slots load a valid j; M=0 kills the product), deg/curs=0.
// ---------------------------------------------------------------------------
__global__ __launch_bounds__(256) void init_ws(int4* __restrict__ winner4,
                                               float4* __restrict__ Mlist4,
                                               int* __restrict__ jlist,
                                               int* __restrict__ deg,
                                               int* __restrict__ curs) {
  const int t = blockIdx.x * 256 + threadIdx.x;  // grid 1681*256 = 430336
  Mlist4[t] = make_float4(0.f, 0.f, 0.f, 0.f);   // 26896*64/4 = 430336 exact
  if (t < 147456) winner4[t] = make_int4(-1, -1, -1, -1);
  if (t < NPAD_SLOTS) jlist[t] = 0;
  if (t < 1024) { deg[t] = 0; curs[t] = 0; }
}

// ---------------------------------------------------------------------------
// Transpose mtr [i][j][8] f32 -> mtrT [j][i][8] bf16 (A-operand for contract).
// ---------------------------------------------------------------------------
__global__ __launch_bounds__(256) void transpose_mtr_bf(
    const float* __restrict__ mtr, uint4* __restrict__ mtrT) {
  __shared__ float lds[16][16 * 8 + 4];
  const int r = threadIdx.x >> 4;
  const int c = threadIdx.x & 15;
  const size_t i0 = (size_t)blockIdx.y * 16;
  const size_t j0 = (size_t)blockIdx.x * 16;

  const float4* src = (const float4*)(mtr + ((i0 + r) * N + (j0 + c)) * 8);
  float4 a = src[0], b = src[1];
  *(float4*)&lds[r][c * 8 + 0] = a;
  *(float4*)&lds[r][c * 8 + 4] = b;
  __syncthreads();
  float4 ta = *(float4*)&lds[c][r * 8 + 0];
  float4 tb = *(float4*)&lds[c][r * 8 + 4];
  uint4 o;
  o.x = pk2(ta.x, ta.y); o.y = pk2(ta.z, ta.w);
  o.z = pk2(tb.x, tb.y); o.w = pk2(tb.z, tb.w);
  mtrT[(j0 + r) * N + (i0 + c)] = o;  // 16 B per (j,i)
}

// ---------------------------------------------------------------------------
// Pre-pass: winner marking + dst-degree histogram.
// ---------------------------------------------------------------------------
__global__ __launch_bounds__(256) void edge_prep(
    const int* __restrict__ ei, int* __restrict__ winner,
    int* __restrict__ deg) {
  const int e = blockIdx.x * 256 + threadIdx.x;
  if (e >= E) return;
  const int s = ei[e];
  const int d = ei[E + e];
  atomicMax(&winner[(size_t)s * N + d], e);
  atomicAdd(&deg[d], 1);
}

// ---------------------------------------------------------------------------
// Exclusive scan of PADDED deg (ceil4) -> offs. One wave, 12 values/lane.
// Segments become group-aligned (base % 4 == 0) for the K=32 MFMA groups.
// ---------------------------------------------------------------------------
__global__ void scan_offs(const int* __restrict__ deg, int* __restrict__ offs) {
  const int lane = threadIdx.x;  // 64 threads
  int v[12];
  int s = 0;
#pragma unroll
  for (int z = 0; z < 12; ++z) {
    v[z] = (deg[lane * 12 + z] + 3) & ~3;
    s += v[z];
  }
  int inc = s;
#pragma unroll
  for (int d = 1; d < 64; d <<= 1) {
    int t = __shfl_up(inc, d, 64);
    if (lane >= d) inc += t;
  }
  int run = inc - s;
#pragma unroll
  for (int z = 0; z < 12; ++z) {
    run += v[z];
    offs[lane * 12 + z + 1] = run;
  }
  if (lane == 0) offs[0] = 0;
}

// ---------------------------------------------------------------------------
// Assign CSR slots to WINNING edges.
// ---------------------------------------------------------------------------
__global__ __launch_bounds__(256) void scatter_pos(
    const int* __restrict__ ei, const int* __restrict__ winner,
    const int* __restrict__ offs, int* __restrict__ curs,
    int* __restrict__ jlist, int* __restrict__ epos) {
  const int e = blockIdx.x * 256 + threadIdx.x;
  if (e >= E) return;
  const int s = ei[e];
  const int d = ei[E + e];
  if (winner[(size_t)s * N + d] != e) { epos[e] = -1; return; }
  const int pos = offs[d] + atomicAdd(&curs[d], 1);
  jlist[pos] = s;
  epos[e] = pos;
}

// ---------------------------------------------------------------------------
// Edge MLP via MFMA (unchanged from round 8): 16 edges/wave, 10 MFMAs,
// winners stored into padded-CSR order (Mlist[pos][64] f32 row-major).
// ---------------------------------------------------------------------------
__global__ __launch_bounds__(64) void edge_mlp_mfma(
    const float* __restrict__ feat, const int* __restrict__ ei,
    const float* __restrict__ ea, const int* __restrict__ epos,
    const float* __restrict__ w0, const float* __restrict__ b0,
    const float* __restrict__ w1, const float* __restrict__ b1,
    const float* __restrict__ w2, const float* __restrict__ b2,
    const float* __restrict__ w3, const float* __restrict__ b3,
    float* __restrict__ Mlist) {
  const int col = threadIdx.x & 15;
  const int hi = (threadIdx.x >> 4) & 3;
  const int e = blockIdx.x * 16 + col;

  const float4 z4 = make_float4(0.f, 0.f, 0.f, 0.f);

  const int s = ei[e];
  const int d = ei[E + e];
  const int pos = epos[e];
  const float* pa = (hi == 0) ? (ea + (size_t)e * 4)
                  : (hi == 1) ? (feat + (size_t)s * 8)
                  : (hi == 2) ? (feat + (size_t)s * 8 + 4)
                              : (feat + (size_t)d * 8);
  float4 va = *(const float4*)pa;
  float4 vb = (hi == 0) ? *(const float4*)(feat + (size_t)d * 8 + 4) : z4;
  bf16x8 bfr = pack_frag(va, vb);

  bf16x8 a0lo, a0hi, a1lo, a1hi, a2lo, a2hi, a3f[4];
  {
    const float* p = w0 + col * 20;
    float4 xa = *(const float4*)(p + hi * 4);
    float4 xb = (hi == 0) ? *(const float4*)(p + 16) : z4;
    a0lo = pack_frag(xa, xb);
    const float* q = w0 + (col + 16) * 20;
    float4 ya = *(const float4*)(q + hi * 4);
    float4 yb = (hi == 0) ? *(const float4*)(q + 16) : z4;
    a0hi = pack_frag(ya, yb);
  }
  a1lo = pack_frag(*(const float4*)(w1 + col * 32 + hi * 4),
                   *(const float4*)(w1 + col * 32 + 16 + hi * 4));
  a1hi = pack_frag(*(const float4*)(w1 + (col + 16) * 32 + hi * 4),
                   *(const float4*)(w1 + (col + 16) * 32 + 16 + hi * 4));
  a2lo = pack_frag(*(const float4*)(w2 + col * 32 + hi * 4),
                   *(const float4*)(w2 + col * 32 + 16 + hi * 4));
  a2hi = pack_frag(*(const float4*)(w2 + (col + 16) * 32 + hi * 4),
                   *(const float4*)(w2 + (col + 16) * 32 + 16 + hi * 4));
#pragma unroll
  for (int q = 0; q < 4; ++q) {
    const float* p = w3 + (size_t)(q * 16 + col) * 32;
    a3f[q] = pack_frag(*(const float4*)(p + hi * 4),
                       *(const float4*)(p + 16 + hi * 4));
  }

  f32x4 d1 = ld4(b0 + hi * 4), d2 = ld4(b0 + 16 + hi * 4);
  d1 = __builtin_amdgcn_mfma_f32_16x16x32_bf16(a0lo, bfr, d1, 0, 0, 0);
  d2 = __builtin_amdgcn_mfma_f32_16x16x32_bf16(a0hi, bfr, d2, 0, 0, 0);
  bfr = relu_pack(d1, d2);

  d1 = ld4(b1 + hi * 4); d2 = ld4(b1 + 16 + hi * 4);
  d1 = __builtin_amdgcn_mfma_f32_16x16x32_bf16(a1lo, bfr, d1, 0, 0, 0);
  d2 = __builtin_amdgcn_mfma_f32_16x16x32_bf16(a1hi, bfr, d2, 0, 0, 0);
  bfr = relu_pack(d1, d2);

  d1 = ld4(b2 + hi * 4); d2 = ld4(b2 + 16 + hi * 4);
  d1 = __builtin_amdgcn_mfma_f32_16x16x32_bf16(a2lo, bfr, d1, 0, 0, 0);
  d2 = __builtin_amdgcn_mfma_f32_16x16x32_bf16(a2hi, bfr, d2, 0, 0, 0);
  bfr = relu_pack(d1, d2);

#pragma unroll
  for (int q = 0; q < 4; ++q) {
    f32x4 d3 = ld4(b3 + q * 16 + hi * 4);
    d3 = __builtin_amdgcn_mfma_f32_16x16x32_bf16(a3f[q], bfr, d3, 0, 0, 0);
    if (pos >= 0) {
      *(float4*)(Mlist + (size_t)pos * 64 + q * 16 + hi * 4) =
          make_float4(d3[0], d3[1], d3[2], d3[3]);
    }
  }
}

// ---------------------------------------------------------------------------
// Repack Mlist (f32, slot-major) -> Mfrag (bf16 B-fragments per K=32 group).
// B[k = g*8+c][n = t]: lane (col=n, hi) gets M_{g=hi>>1}[c=(hi&1)*4+j][col]
// (j0-3) and M_{g=2+(hi>>1)}[...][col] (j4-7); col>=8 lanes are zero (t pad).
// One wave per group, 4 groups per block; zero pad slots pass through.
// ---------------------------------------------------------------------------
__global__ __launch_bounds__(256) void repack_mfrag(
    const float* __restrict__ Mlist, short* __restrict__ Mfrag) {
  __shared__ float L[4][256];
  const int w = threadIdx.x >> 6;
  const int lane = threadIdx.x & 63;
  const int gid = blockIdx.x * 4 + w;  // 0..NGROUPS-1

  *(float4*)&L[w][lane * 4] =
      *(const float4*)(Mlist + (size_t)gid * 256 + lane * 4);
  __syncthreads();

  const int col = lane & 15;
  const int hi = lane >> 4;
  const int g0 = hi >> 1;
  const int c0 = (hi & 1) * 4;

  float a[4] = {0.f, 0.f, 0.f, 0.f}, b[4] = {0.f, 0.f, 0.f, 0.f};
  if (col < 8) {
#pragma unroll
    for (int j = 0; j < 4; ++j) {
      a[j] = L[w][g0 * 64 + (c0 + j) * 8 + col];
      b[j] = L[w][(2 + g0) * 64 + (c0 + j) * 8 + col];
    }
  }
  FragU f;
  f.u[0] = pk2(a[0], a[1]);
  f.u[1] = pk2(a[2], a[3]);
  f.u[2] = pk2(b[0], b[1]);
  f.u[3] = pk2(b[2], b[3]);
  *(bf16x8*)(Mfrag + (size_t)gid * 512 + lane * 8) = f.s;
}

// ---------------------------------------------------------------------------
// Walk contraction v6 — MFMA. Block = 1 k x 256 i (4 waves x 4 D-tiles).
// Per group: 1 B-frag load (16B/lane, reused x4 tiles) + 2x8B A loads/tile,
// acc chained through the C operand. Epilogue: LDS transpose -> coalesced
// 32 B/row stores of WT[k][i][0..7] (= mtr1[i,k,:] / 8).
// k is block-uniform => jlist/offs reads stay scalar (contract4 lesson).
// ---------------------------------------------------------------------------
__global__ __launch_bounds__(256) void contract6(
    const short* __restrict__ mtrT, const short* __restrict__ Mfrag,
    const int* __restrict__ jlist, const int* __restrict__ offs,
    const int* __restrict__ wcnt, float* __restrict__ WT) {
  __shared__ float sD[4][4][16][9];

  const int bid = blockIdx.x;
  const int g = (bid & 7) * 288 + (bid >> 3);  // XCD-chunked: 2304 = 8*288
  const int ig = g / 768;                      // i-slab 0..2 (256 i each)
  const int k = g % 768;
  const int w = threadIdx.x >> 6;
  const int lane = threadIdx.x & 63;
  const int col = lane & 15;
  const int hi = lane >> 4;
  const int ibase = ig * 256 + w * 64;

  const int base = offs[k];   // % 4 == 0 by construction
  const int cnt = wcnt[k];
  const int ngr = (cnt + 3) >> 2;

  f32x4 acc0 = {0.f, 0.f, 0.f, 0.f}, acc1 = {0.f, 0.f, 0.f, 0.f};
  f32x4 acc2 = {0.f, 0.f, 0.f, 0.f}, acc3 = {0.f, 0.f, 0.f, 0.f};

  const size_t lane_off = ((size_t)(ibase + col)) * 8 + (hi & 1) * 4;

#pragma unroll 1
  for (int gg = 0; gg < ngr; ++gg) {
    const int4 js = *(const int4*)(jlist + base + gg * 4);  // uniform
    const int ja = (hi & 2) ? js.y : js.x;
    const int jb = (hi & 2) ? js.w : js.z;

    bf16x8 bfr = *(const bf16x8*)(
        Mfrag + ((size_t)(base >> 2) + gg) * 512 + lane * 8);

    const short* pa = mtrT + (size_t)ja * (N * 8) + lane_off;
    const short* pb = mtrT + (size_t)jb * (N * 8) + lane_off;

#define TILE(ACC, T)                                                     \
  do {                                                                   \
    uint2 ua = *(const uint2*)(pa + (T) * (16 * 8));                     \
    uint2 ub = *(const uint2*)(pb + (T) * (16 * 8));                     \
    FragU af;                                                            \
    af.u[0] = ua.x; af.u[1] = ua.y; af.u[2] = ub.x; af.u[3] = ub.y;      \
    ACC = __builtin_amdgcn_mfma_f32_16x16x32_bf16(af.s, bfr, ACC, 0, 0, 0); \
  } while (0)

    TILE(acc0, 0);
    TILE(acc1, 1);
    TILE(acc2, 2);
    TILE(acc3, 3);
#undef TILE
  }

  // ---- epilogue: D lane (col=t, hi) holds D[i_loc=hi*4+r][t=col] ----
  if (col < 8) {
#pragma unroll
    for (int r = 0; r < 4; ++r) {
      sD[w][0][hi * 4 + r][col] = acc0[r] * 0.125f;
      sD[w][1][hi * 4 + r][col] = acc1[r] * 0.125f;
      sD[w][2][hi * 4 + r][col] = acc2[r] * 0.125f;
      sD[w][3][hi * 4 + r][col] = acc3[r] * 0.125f;
    }
  }
  __syncthreads();
  if (lane < 16) {
#pragma unroll
    for (int t = 0; t < 4; ++t) {
      const float* row = &sD[w][t][lane][0];
      float* dst = WT + ((size_t)k * N + ibase + t * 16 + lane) * 8;
      *(float4*)(dst + 0) = make_float4(row[0], row[1], row[2], row[3]);
      *(float4*)(dst + 4) = make_float4(row[4], row[5], row[6], row[7]);
    }
  }
}

// ---------------------------------------------------------------------------
// Output MLP via MFMA (unchanged from round 7).
// ---------------------------------------------------------------------------
__global__ __launch_bounds__(256, 2) void out_mlp_mfma(
    const float* __restrict__ mtr, const float* __restrict__ WT,
    const float* __restrict__ feat,
    const float* __restrict__ w0, const float* __restrict__ b0,
    const float* __restrict__ w1, const float* __restrict__ b1,
    const float* __restrict__ w2, const float* __restrict__ b2,
    const float* __restrict__ w3, const float* __restrict__ b3,
    float* __restrict__ out) {
  const int i = blockIdx.y;
  const int k0 = blockIdx.x * 256;
  const int w = threadIdx.x >> 6;
  const int col = threadIdx.x & 15;
  const int hi = (threadIdx.x >> 4) & 3;

  bf16x8 a0lo, a0hi, a1lo, a1hi, a2lo, a2hi, a3;
  {
    const float* p = w0 + col * 33;
    float4 xa = make_float4(p[hi * 4], p[hi * 4 + 1], p[hi * 4 + 2], p[hi * 4 + 3]);
    float4 xb = make_float4(p[16 + hi * 4], p[16 + hi * 4 + 1],
                            p[16 + hi * 4 + 2], p[16 + hi * 4 + 3]);
    a0lo = pack_frag(xa, xb);
    const float* q = w0 + (col + 16) * 33;
    float4 ya = make_float4(q[hi * 4], q[hi * 4 + 1], q[hi * 4 + 2], q[hi * 4 + 3]);
    float4 yb = make_float4(q[16 + hi * 4], q[16 + hi * 4 + 1],
                            q[16 + hi * 4 + 2], q[16 + hi * 4 + 3]);
    a0hi = pack_frag(ya, yb);
  }
  a1lo = pack_frag(*(const float4*)(w1 + col * 32 + hi * 4),
                   *(const float4*)(w1 + col * 32 + 16 + hi * 4));
  a1hi = pack_frag(*(const float4*)(w1 + (col + 16) * 32 + hi * 4),
                   *(const float4*)(w1 + (col + 16) * 32 + 16 + hi * 4));
  a2lo = pack_frag(*(const float4*)(w2 + col * 32 + hi * 4),
                   *(const float4*)(w2 + col * 32 + 16 + hi * 4));
  a2hi = pack_frag(*(const float4*)(w2 + (col + 16) * 32 + hi * 4),
                   *(const float4*)(w2 + (col + 16) * 32 + 16 + hi * 4));
  if (col < 8) {
    a3 = pack_frag(*(const float4*)(w3 + col * 32 + hi * 4),
                   *(const float4*)(w3 + col * 32 + 16 + hi * 4));
  } else {
    FragU z; z.u[0] = z.u[1] = z.u[2] = z.u[3] = 0; a3 = z.s;
  }

  const f32x4 c1a = ld4(b0 + hi * 4), c1b = ld4(b0 + 16 + hi * 4);
  const f32x4 c2a = ld4(b1 + hi * 4), c2b = ld4(b1 + 16 + hi * 4);
  const f32x4 c3a = ld4(b2 + hi * 4), c3b = ld4(b2 + 16 + hi * 4);
  f32x4 c4;
  if (hi < 2) c4 = ld4(b3 + hi * 4);
  else { c4[0] = c4[1] = c4[2] = c4[3] = 0.f; }

  float dg1[4], dg2[4];
#pragma unroll
  for (int r = 0; r < 4; ++r) {
    dg1[r] = w0[(hi * 4 + r) * 33 + 32];
    dg2[r] = w0[(16 + hi * 4 + r) * 33 + 32];
  }

#pragma unroll 1
  for (int g = 0; g < 4; ++g) {
    const int krow = k0 + w * 64 + g * 16 + col;

    const float* pA = (hi < 2) ? (WT + ((size_t)krow * N + i) * 8 + (hi & 1) * 4)
                               : (WT + ((size_t)i * N + krow) * 8 + (hi & 1) * 4);
    const float* pB = (hi < 2) ? (feat + (size_t)krow * 8 + (hi & 1) * 4)
                               : (feat + (size_t)i * 8 + (hi & 1) * 4);
    bf16x8 bfr = pack_frag(*(const float4*)pA, *(const float4*)pB);

    f32x4 d1 = c1a, d2 = c1b;
    d1 = __builtin_amdgcn_mfma_f32_16x16x32_bf16(a0lo, bfr, d1, 0, 0, 0);
    d2 = __builtin_amdgcn_mfma_f32_16x16x32_bf16(a0hi, bfr, d2, 0, 0, 0);
    const float eye = (krow == i) ? 1.f : 0.f;
#pragma unroll
    for (int r = 0; r < 4; ++r) {
      d1[r] = fmaf(eye, dg1[r], d1[r]);
      d2[r] = fmaf(eye, dg2[r], d2[r]);
    }
    bfr = relu_pack(d1, d2);

    d1 = c2a; d2 = c2b;
    d1 = __builtin_amdgcn_mfma_f32_16x16x32_bf16(a1lo, bfr, d1, 0, 0, 0);
    d2 = __builtin_amdgcn_mfma_f32_16x16x32_bf16(a1hi, bfr, d2, 0, 0, 0);
    bfr = relu_pack(d1, d2);

    d1 = c3a; d2 = c3b;
    d1 = __builtin_amdgcn_mfma_f32_16x16x32_bf16(a2lo, bfr, d1, 0, 0, 0);
    d2 = __builtin_amdgcn_mfma_f32_16x16x32_bf16(a2hi, bfr, d2, 0, 0, 0);
    bfr = relu_pack(d1, d2);

    f32x4 d3 = c4;
    d3 = __builtin_amdgcn_mfma_f32_16x16x32_bf16(a3, bfr, d3, 0, 0, 0);

    if (hi < 2) {
      const size_t idx = ((size_t)i * N + krow) * 8 + hi * 4;
      float4 m = *(const float4*)(mtr + idx);
      *(float4*)(out + idx) =
          make_float4(m.x + d3[0], m.y + d3[1], m.z + d3[2], m.w + d3[3]);
    }
  }
}

// ---------------------------------------------------------------------------
extern "C" void kernel_launch(void* const* d_in, const int* in_sizes, int n_in,
                              void* d_out, int out_size, void* d_ws,
                              size_t ws_size, hipStream_t stream) {
  const float* mtr  = (const float*)d_in[0];
  const float* feat = (const float*)d_in[1];
  const int*   ei   = (const int*)d_in[2];
  const float* ea   = (const float*)d_in[3];
  const float* ew0 = (const float*)d_in[4];
  const float* eb0 = (const float*)d_in[5];
  const float* ew1 = (const float*)d_in[6];
  const float* eb1 = (const float*)d_in[7];
  const float* ew2 = (const float*)d_in[8];
  const float* eb2 = (const float*)d_in[9];
  const float* ew3 = (const float*)d_in[10];
  const float* eb3 = (const float*)d_in[11];
  const float* ow0 = (const float*)d_in[12];
  const float* ob0 = (const float*)d_in[13];
  const float* ow1 = (const float*)d_in[14];
  const float* ob1 = (const float*)d_in[15];
  const float* ow2 = (const float*)d_in[16];
  const float* ob2 = (const float*)d_in[17];
  const float* ow3 = (const float*)d_in[18];
  const float* ob3 = (const float*)d_in[19];
  float* out = (float*)d_out;

  char* ws = (char*)d_ws;
  float* Mlist = (float*)ws; ws += (size_t)MLIST_SLOTS * 64 * 4;  // 6.89 MB
  short* Mfrag = (short*)ws; ws += (size_t)NGROUPS * 512 * 2;     // 6.88 MB
  short* mtrT  = (short*)ws; ws += (size_t)N * N * 8 * 2;         // 9.44 MB
  float* WT    = (float*)ws; ws += (size_t)N * N * 8 * 4;         // 18.87 MB
  int* winner  = (int*)ws;   ws += (size_t)N * N * 4;             // 2.36 MB
  int* deg     = (int*)ws;   ws += 1024 * 4;
  int* offs    = (int*)ws;   ws += 1024 * 4;
  int* curs    = (int*)ws;   ws += 1024 * 4;
  int* jlist   = (int*)ws;   ws += (size_t)NPAD_SLOTS * 4;        // 108 KB
  int* epos    = (int*)ws;   ws += (size_t)E * 4;                 // 98 KB

  init_ws<<<1681, 256, 0, stream>>>((int4*)winner, (float4*)Mlist, jlist, deg,
                                    curs);
  edge_prep<<<E / 256, 256, 0, stream>>>(ei, winner, deg);
  scan_offs<<<1, 64, 0, stream>>>(deg, offs);
  scatter_pos<<<E / 256, 256, 0, stream>>>(ei, winner, offs, curs, jlist, epos);
  transpose_mtr_bf<<<dim3(48, 48), 256, 0, stream>>>(mtr, (uint4*)mtrT);
  edge_mlp_mfma<<<E / 16, 64, 0, stream>>>(feat, ei, ea, epos, ew0, eb0, ew1,
                                           eb1, ew2, eb2, ew3, eb3, Mlist);
  repack_mfrag<<<NGROUPS / 4, 256, 0, stream>>>(Mlist, Mfrag);
  contract6<<<2304, 256, 0, stream>>>(mtrT, Mfrag, jlist, offs, curs, WT);
  out_mlp_mfma<<<dim3(3, N), 256, 0, stream>>>(mtr, WT, feat, ow0, ob0, ow1,
                                               ob1, ow2, ob2, ow3, ob3, out);
}

// Round 10
// 93.720 us; speedup vs baseline: 2.2403x; 1.1263x over previous
//
#include <hip/hip_runtime.h>

#define N 768
#define E 24576
#define NPAD_SLOTS (E + 3 * 768)      // 26880 max padded CSR slots
#define NGROUPS (NPAD_SLOTS / 4)      // 6720 K=32 groups
#define MLIST_SLOTS (NPAD_SLOTS + 16) // 26896 (alloc pad)

typedef __attribute__((ext_vector_type(8))) short bf16x8;
typedef __attribute__((ext_vector_type(4))) float f32x4;

// ---------------------------------------------------------------------------
// MFMA helpers — slot convention validated on HW (rounds 7-9):
// A/B lane (col, hi): slots j0-3 = k=hi*4+j, j4-7 = k=16+hi*4+j (lo 16b = even)
// C/D lane (col, hi): D[row = hi*4+r][col].
// ---------------------------------------------------------------------------
__device__ __forceinline__ unsigned pk2(float lo, float hi) {
  unsigned r;
  asm("v_cvt_pk_bf16_f32 %0, %1, %2" : "=v"(r) : "v"(lo), "v"(hi));
  return r;
}

union FragU {
  unsigned u[4];
  bf16x8 s;
};

__device__ __forceinline__ bf16x8 pack_frag(float4 a, float4 b) {
  FragU f;
  f.u[0] = pk2(a.x, a.y);
  f.u[1] = pk2(a.z, a.w);
  f.u[2] = pk2(b.x, b.y);
  f.u[3] = pk2(b.z, b.w);
  return f.s;
}

__device__ __forceinline__ bf16x8 relu_pack(f32x4 d1, f32x4 d2) {
  FragU f;
  f.u[0] = pk2(fmaxf(d1[0], 0.f), fmaxf(d1[1], 0.f));
  f.u[1] = pk2(fmaxf(d1[2], 0.f), fmaxf(d1[3], 0.f));
  f.u[2] = pk2(fmaxf(d2[0], 0.f), fmaxf(d2[1], 0.f));
  f.u[3] = pk2(fmaxf(d2[2], 0.f), fmaxf(d2[3], 0.f));
  return f.s;
}

__device__ __forceinline__ f32x4 ld4(const float* p) {
  float4 v = *(const float4*)p;
  f32x4 r;
  r[0] = v.x; r[1] = v.y; r[2] = v.z; r[3] = v.w;
  return r;
}

// ---------------------------------------------------------------------------
// prep0 = transpose (blocks 0..2303) + workspace init (blocks 2304..3984).
// mtr [i][j][8] f32 -> mtrT [j][i][8] bf16; winner=-1; Mlist=0 (pad slots
// must contribute 0); jlist=0; deg/curs/done_ctr=0.
// ---------------------------------------------------------------------------
__global__ __launch_bounds__(256) void prep0(
    const float* __restrict__ mtr, uint4* __restrict__ mtrT,
    int4* __restrict__ winner4, float4* __restrict__ Mlist4,
    int* __restrict__ jlist, int* __restrict__ deg, int* __restrict__ curs,
    int* __restrict__ done_ctr) {
  __shared__ float lds[16][16 * 8 + 4];
  if (blockIdx.x < 2304) {
    const int r = threadIdx.x >> 4;
    const int c = threadIdx.x & 15;
    const size_t j0 = (size_t)(blockIdx.x % 48) * 16;
    const size_t i0 = (size_t)(blockIdx.x / 48) * 16;

    const float4* src = (const float4*)(mtr + ((i0 + r) * N + (j0 + c)) * 8);
    float4 a = src[0], b = src[1];
    *(float4*)&lds[r][c * 8 + 0] = a;
    *(float4*)&lds[r][c * 8 + 4] = b;
    __syncthreads();
    float4 ta = *(float4*)&lds[c][r * 8 + 0];
    float4 tb = *(float4*)&lds[c][r * 8 + 4];
    uint4 o;
    o.x = pk2(ta.x, ta.y); o.y = pk2(ta.z, ta.w);
    o.z = pk2(tb.x, tb.y); o.w = pk2(tb.z, tb.w);
    mtrT[(j0 + r) * N + (i0 + c)] = o;
  } else {
    const int t = (blockIdx.x - 2304) * 256 + threadIdx.x;  // < 430336 exact
    Mlist4[t] = make_float4(0.f, 0.f, 0.f, 0.f);
    if (t < 147456) winner4[t] = make_int4(-1, -1, -1, -1);
    if (t < NPAD_SLOTS) jlist[t] = 0;
    if (t < 1024) { deg[t] = 0; curs[t] = 0; }
    if (t == 0) *done_ctr = 0;
  }
}

// ---------------------------------------------------------------------------
// edge_prep + last-block fused scan: winner atomicMax, deg histogram;
// the last block to finish (ticket == 95) performs the padded (ceil4)
// exclusive scan with one wave, reading deg via atomic adds (coherent).
// offs consumed by the NEXT dispatch (cross-dispatch visibility guaranteed).
// ---------------------------------------------------------------------------
__global__ __launch_bounds__(256) void edge_prep_scan(
    const int* __restrict__ ei, int* __restrict__ winner,
    int* __restrict__ deg, int* __restrict__ offs,
    int* __restrict__ done_ctr) {
  const int e = blockIdx.x * 256 + threadIdx.x;  // grid 96*256 = E exact
  const int s = ei[e];
  const int d = ei[E + e];
  atomicMax(&winner[(size_t)s * N + d], e);
  atomicAdd(&deg[d], 1);

  __threadfence();
  __syncthreads();
  __shared__ int ticket;
  if (threadIdx.x == 0) ticket = atomicAdd(done_ctr, 1);
  __syncthreads();
  if (ticket == (E / 256) - 1 && threadIdx.x < 64) {
    const int lane = threadIdx.x;
    int v[12];
    int sum = 0;
#pragma unroll
    for (int z = 0; z < 12; ++z) {
      v[z] = (atomicAdd(&deg[lane * 12 + z], 0) + 3) & ~3;  // ceil4 pad
      sum += v[z];
    }
    int inc = sum;
#pragma unroll
    for (int dd = 1; dd < 64; dd <<= 1) {
      int t = __shfl_up(inc, dd, 64);
      if (lane >= dd) inc += t;
    }
    int run = inc - sum;
#pragma unroll
    for (int z = 0; z < 12; ++z) {
      run += v[z];
      offs[lane * 12 + z + 1] = run;
    }
    if (lane == 0) offs[0] = 0;
  }
}

// ---------------------------------------------------------------------------
// Edge MLP via MFMA with fused CSR-slot scatter. 4 waves/block, 16 edges/wave.
// hi==0 lane claims the slot (winner check + atomicAdd) and writes jlist;
// pos broadcast to the other 3 lanes of the edge via shfl.
// ---------------------------------------------------------------------------
__global__ __launch_bounds__(256) void edge_mlp_mfma(
    const float* __restrict__ feat, const int* __restrict__ ei,
    const float* __restrict__ ea, const int* __restrict__ winner,
    const int* __restrict__ offs, int* __restrict__ curs,
    int* __restrict__ jlist,
    const float* __restrict__ w0, const float* __restrict__ b0,
    const float* __restrict__ w1, const float* __restrict__ b1,
    const float* __restrict__ w2, const float* __restrict__ b2,
    const float* __restrict__ w3, const float* __restrict__ b3,
    float* __restrict__ Mlist) {
  const int wv = threadIdx.x >> 6;
  const int lane = threadIdx.x & 63;
  const int col = lane & 15;
  const int hi = lane >> 4;
  const int e = (blockIdx.x * 4 + wv) * 16 + col;

  const float4 z4 = make_float4(0.f, 0.f, 0.f, 0.f);

  const int s = ei[e];
  const int d = ei[E + e];
  int pos = -1;
  if (hi == 0) {
    if (winner[(size_t)s * N + d] == e) {
      pos = offs[d] + atomicAdd(&curs[d], 1);
      jlist[pos] = s;
    }
  }
  pos = __shfl(pos, col, 64);

  const float* pa = (hi == 0) ? (ea + (size_t)e * 4)
                  : (hi == 1) ? (feat + (size_t)s * 8)
                  : (hi == 2) ? (feat + (size_t)s * 8 + 4)
                              : (feat + (size_t)d * 8);
  float4 va = *(const float4*)pa;
  float4 vb = (hi == 0) ? *(const float4*)(feat + (size_t)d * 8 + 4) : z4;
  bf16x8 bfr = pack_frag(va, vb);

  bf16x8 a0lo, a0hi, a1lo, a1hi, a2lo, a2hi, a3f[4];
  {
    const float* p = w0 + col * 20;
    float4 xa = *(const float4*)(p + hi * 4);
    float4 xb = (hi == 0) ? *(const float4*)(p + 16) : z4;
    a0lo = pack_frag(xa, xb);
    const float* q = w0 + (col + 16) * 20;
    float4 ya = *(const float4*)(q + hi * 4);
    float4 yb = (hi == 0) ? *(const float4*)(q + 16) : z4;
    a0hi = pack_frag(ya, yb);
  }
  a1lo = pack_frag(*(const float4*)(w1 + col * 32 + hi * 4),
                   *(const float4*)(w1 + col * 32 + 16 + hi * 4));
  a1hi = pack_frag(*(const float4*)(w1 + (col + 16) * 32 + hi * 4),
                   *(const float4*)(w1 + (col + 16) * 32 + 16 + hi * 4));
  a2lo = pack_frag(*(const float4*)(w2 + col * 32 + hi * 4),
                   *(const float4*)(w2 + col * 32 + 16 + hi * 4));
  a2hi = pack_frag(*(const float4*)(w2 + (col + 16) * 32 + hi * 4),
                   *(const float4*)(w2 + (col + 16) * 32 + 16 + hi * 4));
#pragma unroll
  for (int q = 0; q < 4; ++q) {
    const float* p = w3 + (size_t)(q * 16 + col) * 32;
    a3f[q] = pack_frag(*(const float4*)(p + hi * 4),
                       *(const float4*)(p + 16 + hi * 4));
  }

  f32x4 d1 = ld4(b0 + hi * 4), d2 = ld4(b0 + 16 + hi * 4);
  d1 = __builtin_amdgcn_mfma_f32_16x16x32_bf16(a0lo, bfr, d1, 0, 0, 0);
  d2 = __builtin_amdgcn_mfma_f32_16x16x32_bf16(a0hi, bfr, d2, 0, 0, 0);
  bfr = relu_pack(d1, d2);

  d1 = ld4(b1 + hi * 4); d2 = ld4(b1 + 16 + hi * 4);
  d1 = __builtin_amdgcn_mfma_f32_16x16x32_bf16(a1lo, bfr, d1, 0, 0, 0);
  d2 = __builtin_amdgcn_mfma_f32_16x16x32_bf16(a1hi, bfr, d2, 0, 0, 0);
  bfr = relu_pack(d1, d2);

  d1 = ld4(b2 + hi * 4); d2 = ld4(b2 + 16 + hi * 4);
  d1 = __builtin_amdgcn_mfma_f32_16x16x32_bf16(a2lo, bfr, d1, 0, 0, 0);
  d2 = __builtin_amdgcn_mfma_f32_16x16x32_bf16(a2hi, bfr, d2, 0, 0, 0);
  bfr = relu_pack(d1, d2);

#pragma unroll
  for (int q = 0; q < 4; ++q) {
    f32x4 d3 = ld4(b3 + q * 16 + hi * 4);
    d3 = __builtin_amdgcn_mfma_f32_16x16x32_bf16(a3f[q], bfr, d3, 0, 0, 0);
    if (pos >= 0) {
      *(float4*)(Mlist + (size_t)pos * 64 + q * 16 + hi * 4) =
          make_float4(d3[0], d3[1], d3[2], d3[3]);
    }
  }
}

// ---------------------------------------------------------------------------
// Repack Mlist (f32, slot-major) -> Mfrag (bf16 B-fragments per K=32 group).
// Zero pad slots pass through as zero fragments.
// ---------------------------------------------------------------------------
__global__ __launch_bounds__(256) void repack_mfrag(
    const float* __restrict__ Mlist, short* __restrict__ Mfrag) {
  __shared__ float L[4][256];
  const int w = threadIdx.x >> 6;
  const int lane = threadIdx.x & 63;
  const int gid = blockIdx.x * 4 + w;  // 0..NGROUPS-1

  *(float4*)&L[w][lane * 4] =
      *(const float4*)(Mlist + (size_t)gid * 256 + lane * 4);
  __syncthreads();

  const int col = lane & 15;
  const int hi = lane >> 4;
  const int g0 = hi >> 1;
  const int c0 = (hi & 1) * 4;

  float a[4] = {0.f, 0.f, 0.f, 0.f}, b[4] = {0.f, 0.f, 0.f, 0.f};
  if (col < 8) {
#pragma unroll
    for (int j = 0; j < 4; ++j) {
      a[j] = L[w][g0 * 64 + (c0 + j) * 8 + col];
      b[j] = L[w][(2 + g0) * 64 + (c0 + j) * 8 + col];
    }
  }
  FragU f;
  f.u[0] = pk2(a[0], a[1]);
  f.u[1] = pk2(a[2], a[3]);
  f.u[2] = pk2(b[0], b[1]);
  f.u[3] = pk2(b[2], b[3]);
  *(bf16x8*)(Mfrag + (size_t)gid * 512 + lane * 8) = f.s;
}

// ---------------------------------------------------------------------------
// Walk contraction v7 — MFMA, WT output in bf16.
// Block = 1 k x 256 i (4 waves x 4 D-tiles); XCD-chunked.
// ---------------------------------------------------------------------------
__global__ __launch_bounds__(256) void contract7(
    const short* __restrict__ mtrT, const short* __restrict__ Mfrag,
    const int* __restrict__ jlist, const int* __restrict__ offs,
    const int* __restrict__ wcnt, short* __restrict__ WTb) {
  __shared__ float sD[4][4][16][9];

  const int bid = blockIdx.x;
  const int g = (bid & 7) * 288 + (bid >> 3);  // XCD-chunked: 2304 = 8*288
  const int ig = g / 768;                      // i-slab 0..2 (256 i each)
  const int k = g % 768;
  const int w = threadIdx.x >> 6;
  const int lane = threadIdx.x & 63;
  const int col = lane & 15;
  const int hi = lane >> 4;
  const int ibase = ig * 256 + w * 64;

  const int base = offs[k];   // % 4 == 0 by construction
  const int cnt = wcnt[k];
  const int ngr = (cnt + 3) >> 2;

  f32x4 acc0 = {0.f, 0.f, 0.f, 0.f}, acc1 = {0.f, 0.f, 0.f, 0.f};
  f32x4 acc2 = {0.f, 0.f, 0.f, 0.f}, acc3 = {0.f, 0.f, 0.f, 0.f};

  const size_t lane_off = ((size_t)(ibase + col)) * 8 + (hi & 1) * 4;

#pragma unroll 1
  for (int gg = 0; gg < ngr; ++gg) {
    const int4 js = *(const int4*)(jlist + base + gg * 4);  // uniform
    const int ja = (hi & 2) ? js.y : js.x;
    const int jb = (hi & 2) ? js.w : js.z;

    bf16x8 bfr = *(const bf16x8*)(
        Mfrag + ((size_t)(base >> 2) + gg) * 512 + lane * 8);

    const short* pa = mtrT + (size_t)ja * (N * 8) + lane_off;
    const short* pb = mtrT + (size_t)jb * (N * 8) + lane_off;

#define TILE(ACC, T)                                                     \
  do {                                                                   \
    uint2 ua = *(const uint2*)(pa + (T) * (16 * 8));                     \
    uint2 ub = *(const uint2*)(pb + (T) * (16 * 8));                     \
    FragU af;                                                            \
    af.u[0] = ua.x; af.u[1] = ua.y; af.u[2] = ub.x; af.u[3] = ub.y;      \
    ACC = __builtin_amdgcn_mfma_f32_16x16x32_bf16(af.s, bfr, ACC, 0, 0, 0); \
  } while (0)

    TILE(acc0, 0);
    TILE(acc1, 1);
    TILE(acc2, 2);
    TILE(acc3, 3);
#undef TILE
  }

  // ---- epilogue: D lane (col=t, hi) holds D[i_loc=hi*4+r][t=col] ----
  if (col < 8) {
#pragma unroll
    for (int r = 0; r < 4; ++r) {
      sD[w][0][hi * 4 + r][col] = acc0[r] * 0.125f;
      sD[w][1][hi * 4 + r][col] = acc1[r] * 0.125f;
      sD[w][2][hi * 4 + r][col] = acc2[r] * 0.125f;
      sD[w][3][hi * 4 + r][col] = acc3[r] * 0.125f;
    }
  }
  __syncthreads();
  if (lane < 16) {
#pragma unroll
    for (int t = 0; t < 4; ++t) {
      const float* row = &sD[w][t][lane][0];
      uint4 o;
      o.x = pk2(row[0], row[1]); o.y = pk2(row[2], row[3]);
      o.z = pk2(row[4], row[5]); o.w = pk2(row[6], row[7]);
      *(uint4*)(WTb + ((size_t)k * N + ibase + t * 16 + lane) * 8) = o;
    }
  }
}

// ---------------------------------------------------------------------------
// Output MLP via MFMA. WT read as bf16 (direct bit reuse for channels 0-15);
// one block per i, 12 k-groups per wave (weight-frag setup amortized 3x).
// ---------------------------------------------------------------------------
__global__ __launch_bounds__(256, 2) void out_mlp_mfma(
    const float* __restrict__ mtr, const short* __restrict__ WTb,
    const float* __restrict__ feat,
    const float* __restrict__ w0, const float* __restrict__ b0,
    const float* __restrict__ w1, const float* __restrict__ b1,
    const float* __restrict__ w2, const float* __restrict__ b2,
    const float* __restrict__ w3, const float* __restrict__ b3,
    float* __restrict__ out) {
  const int i = blockIdx.x;
  const int w = threadIdx.x >> 6;
  const int col = threadIdx.x & 15;
  const int hi = (threadIdx.x >> 4) & 3;

  bf16x8 a0lo, a0hi, a1lo, a1hi, a2lo, a2hi, a3;
  {
    const float* p = w0 + col * 33;
    float4 xa = make_float4(p[hi * 4], p[hi * 4 + 1], p[hi * 4 + 2], p[hi * 4 + 3]);
    float4 xb = make_float4(p[16 + hi * 4], p[16 + hi * 4 + 1],
                            p[16 + hi * 4 + 2], p[16 + hi * 4 + 3]);
    a0lo = pack_frag(xa, xb);
    const float* q = w0 + (col + 16) * 33;
    float4 ya = make_float4(q[hi * 4], q[hi * 4 + 1], q[hi * 4 + 2], q[hi * 4 + 3]);
    float4 yb = make_float4(q[16 + hi * 4], q[16 + hi * 4 + 1],
                            q[16 + hi * 4 + 2], q[16 + hi * 4 + 3]);
    a0hi = pack_frag(ya, yb);
  }
  a1lo = pack_frag(*(const float4*)(w1 + col * 32 + hi * 4),
                   *(const float4*)(w1 + col * 32 + 16 + hi * 4));
  a1hi = pack_frag(*(const float4*)(w1 + (col + 16) * 32 + hi * 4),
                   *(const float4*)(w1 + (col + 16) * 32 + 16 + hi * 4));
  a2lo = pack_frag(*(const float4*)(w2 + col * 32 + hi * 4),
                   *(const float4*)(w2 + col * 32 + 16 + hi * 4));
  a2hi = pack_frag(*(const float4*)(w2 + (col + 16) * 32 + hi * 4),
                   *(const float4*)(w2 + (col + 16) * 32 + 16 + hi * 4));
  if (col < 8) {
    a3 = pack_frag(*(const float4*)(w3 + col * 32 + hi * 4),
                   *(const float4*)(w3 + col * 32 + 16 + hi * 4));
  } else {
    FragU z; z.u[0] = z.u[1] = z.u[2] = z.u[3] = 0; a3 = z.s;
  }

  const f32x4 c1a = ld4(b0 + hi * 4), c1b = ld4(b0 + 16 + hi * 4);
  const f32x4 c2a = ld4(b1 + hi * 4), c2b = ld4(b1 + 16 + hi * 4);
  const f32x4 c3a = ld4(b2 + hi * 4), c3b = ld4(b2 + 16 + hi * 4);
  f32x4 c4;
  if (hi < 2) c4 = ld4(b3 + hi * 4);
  else { c4[0] = c4[1] = c4[2] = c4[3] = 0.f; }

  float dg1[4], dg2[4];
#pragma unroll
  for (int r = 0; r < 4; ++r) {
    dg1[r] = w0[(hi * 4 + r) * 33 + 32];
    dg2[r] = w0[(16 + hi * 4 + r) * 33 + 32];
  }

#pragma unroll 1
  for (int g = 0; g < 12; ++g) {
    const int krow = w * 192 + g * 16 + col;

    FragU bf;
    const short* pW = (hi < 2)
        ? (WTb + ((size_t)krow * N + i) * 8 + (hi & 1) * 4)
        : (WTb + ((size_t)i * N + krow) * 8 + (hi & 1) * 4);
    uint2 wv2 = *(const uint2*)pW;
    const float* pF = (hi < 2) ? (feat + (size_t)krow * 8 + (hi & 1) * 4)
                               : (feat + (size_t)i * 8 + (hi & 1) * 4);
    float4 fv = *(const float4*)pF;
    bf.u[0] = wv2.x; bf.u[1] = wv2.y;
    bf.u[2] = pk2(fv.x, fv.y); bf.u[3] = pk2(fv.z, fv.w);
    bf16x8 bfr = bf.s;

    f32x4 d1 = c1a, d2 = c1b;
    d1 = __builtin_amdgcn_mfma_f32_16x16x32_bf16(a0lo, bfr, d1, 0, 0, 0);
    d2 = __builtin_amdgcn_mfma_f32_16x16x32_bf16(a0hi, bfr, d2, 0, 0, 0);
    const float eye = (krow == i) ? 1.f : 0.f;
#pragma unroll
    for (int r = 0; r < 4; ++r) {
      d1[r] = fmaf(eye, dg1[r], d1[r]);
      d2[r] = fmaf(eye, dg2[r], d2[r]);
    }
    bfr = relu_pack(d1, d2);

    d1 = c2a; d2 = c2b;
    d1 = __builtin_amdgcn_mfma_f32_16x16x32_bf16(a1lo, bfr, d1, 0, 0, 0);
    d2 = __builtin_amdgcn_mfma_f32_16x16x32_bf16(a1hi, bfr, d2, 0, 0, 0);
    bfr = relu_pack(d1, d2);

    d1 = c3a; d2 = c3b;
    d1 = __builtin_amdgcn_mfma_f32_16x16x32_bf16(a2lo, bfr, d1, 0, 0, 0);
    d2 = __builtin_amdgcn_mfma_f32_16x16x32_bf16(a2hi, bfr, d2, 0, 0, 0);
    bfr = relu_pack(d1, d2);

    f32x4 d3 = c4;
    d3 = __builtin_amdgcn_mfma_f32_16x16x32_bf16(a3, bfr, d3, 0, 0, 0);

    if (hi < 2) {
      const size_t idx = ((size_t)i * N + krow) * 8 + hi * 4;
      float4 m = *(const float4*)(mtr + idx);
      *(float4*)(out + idx) =
          make_float4(m.x + d3[0], m.y + d3[1], m.z + d3[2], m.w + d3[3]);
    }
  }
}

// ---------------------------------------------------------------------------
extern "C" void kernel_launch(void* const* d_in, const int* in_sizes, int n_in,
                              void* d_out, int out_size, void* d_ws,
                              size_t ws_size, hipStream_t stream) {
  const float* mtr  = (const float*)d_in[0];
  const float* feat = (const float*)d_in[1];
  const int*   ei   = (const int*)d_in[2];
  const float* ea   = (const float*)d_in[3];
  const float* ew0 = (const float*)d_in[4];
  const float* eb0 = (const float*)d_in[5];
  const float* ew1 = (const float*)d_in[6];
  const float* eb1 = (const float*)d_in[7];
  const float* ew2 = (const float*)d_in[8];
  const float* eb2 = (const float*)d_in[9];
  const float* ew3 = (const float*)d_in[10];
  const float* eb3 = (const float*)d_in[11];
  const float* ow0 = (const float*)d_in[12];
  const float* ob0 = (const float*)d_in[13];
  const float* ow1 = (const float*)d_in[14];
  const float* ob1 = (const float*)d_in[15];
  const float* ow2 = (const float*)d_in[16];
  const float* ob2 = (const float*)d_in[17];
  const float* ow3 = (const float*)d_in[18];
  const float* ob3 = (const float*)d_in[19];
  float* out = (float*)d_out;

  char* ws = (char*)d_ws;
  float* Mlist = (float*)ws; ws += (size_t)MLIST_SLOTS * 64 * 4;  // 6.89 MB
  short* Mfrag = (short*)ws; ws += (size_t)NGROUPS * 512 * 2;     // 6.88 MB
  short* mtrT  = (short*)ws; ws += (size_t)N * N * 8 * 2;         // 9.44 MB
  short* WTb   = (short*)ws; ws += (size_t)N * N * 8 * 2;         // 9.44 MB
  int* winner  = (int*)ws;   ws += (size_t)N * N * 4;             // 2.36 MB
  int* deg     = (int*)ws;   ws += 1024 * 4;
  int* offs    = (int*)ws;   ws += 1024 * 4;
  int* curs    = (int*)ws;   ws += 1024 * 4;
  int* done_ctr = (int*)ws;  ws += 256 * 4;
  int* jlist   = (int*)ws;   ws += (size_t)NPAD_SLOTS * 4;        // 108 KB

  prep0<<<2304 + 1681, 256, 0, stream>>>(mtr, (uint4*)mtrT, (int4*)winner,
                                         (float4*)Mlist, jlist, deg, curs,
                                         done_ctr);
  edge_prep_scan<<<E / 256, 256, 0, stream>>>(ei, winner, deg, offs, done_ctr);
  edge_mlp_mfma<<<E / 64, 256, 0, stream>>>(feat, ei, ea, winner, offs, curs,
                                            jlist, ew0, eb0, ew1, eb1, ew2,
                                            eb2, ew3, eb3, Mlist);
  repack_mfrag<<<NGROUPS / 4, 256, 0, stream>>>(Mlist, Mfrag);
  contract7<<<2304, 256, 0, stream>>>(mtrT, Mfrag, jlist, offs, curs, WTb);
  out_mlp_mfma<<<N, 256, 0, stream>>>(mtr, WTb, feat, ow0, ob0, ow1, ob1, ow2,
                                      ob2, ow3, ob3, out);
}

// Round 11
// 91.083 us; speedup vs baseline: 2.3051x; 1.0290x over previous
//
#include <hip/hip_runtime.h>

#define N 768
#define E 24576
#define NPAD_SLOTS (E + 3 * 768)      // 26880 max padded CSR slots
#define NGROUPS (NPAD_SLOTS / 4)      // 6720 K=32 groups

typedef __attribute__((ext_vector_type(8))) short bf16x8;
typedef __attribute__((ext_vector_type(4))) float f32x4;

// ---------------------------------------------------------------------------
// MFMA helpers — slot convention validated on HW (rounds 7-10):
// A/B lane (col, hi): slots j0-3 = k=hi*4+j, j4-7 = k=16+hi*4+j (lo 16b = even)
// C/D lane (col, hi): D[row = hi*4+r][col].
// ---------------------------------------------------------------------------
__device__ __forceinline__ unsigned pk2(float lo, float hi) {
  unsigned r;
  asm("v_cvt_pk_bf16_f32 %0, %1, %2" : "=v"(r) : "v"(lo), "v"(hi));
  return r;
}

union FragU {
  unsigned u[4];
  bf16x8 s;
};

__device__ __forceinline__ bf16x8 pack_frag(float4 a, float4 b) {
  FragU f;
  f.u[0] = pk2(a.x, a.y);
  f.u[1] = pk2(a.z, a.w);
  f.u[2] = pk2(b.x, b.y);
  f.u[3] = pk2(b.z, b.w);
  return f.s;
}

__device__ __forceinline__ bf16x8 relu_pack(f32x4 d1, f32x4 d2) {
  FragU f;
  f.u[0] = pk2(fmaxf(d1[0], 0.f), fmaxf(d1[1], 0.f));
  f.u[1] = pk2(fmaxf(d1[2], 0.f), fmaxf(d1[3], 0.f));
  f.u[2] = pk2(fmaxf(d2[0], 0.f), fmaxf(d2[1], 0.f));
  f.u[3] = pk2(fmaxf(d2[2], 0.f), fmaxf(d2[3], 0.f));
  return f.s;
}

__device__ __forceinline__ f32x4 ld4(const float* p) {
  float4 v = *(const float4*)p;
  f32x4 r;
  r[0] = v.x; r[1] = v.y; r[2] = v.z; r[3] = v.w;
  return r;
}

// ---------------------------------------------------------------------------
// prep0 = transpose (blocks 0..2303) + workspace init (blocks 2304..3983).
// mtr [i][j][8] f32 -> mtrT [j][i][8] bf16; winner=-1; Mfrag=0 (pad slots
// and t>=8 columns must read as zero fragments); jlist=0; deg/curs/ctr=0.
// ---------------------------------------------------------------------------
__global__ __launch_bounds__(256) void prep0(
    const float* __restrict__ mtr, uint4* __restrict__ mtrT,
    int4* __restrict__ winner4, uint4* __restrict__ Mfrag4,
    int* __restrict__ jlist, int* __restrict__ deg, int* __restrict__ curs,
    int* __restrict__ done_ctr) {
  __shared__ float lds[16][16 * 8 + 4];
  if (blockIdx.x < 2304) {
    const int r = threadIdx.x >> 4;
    const int c = threadIdx.x & 15;
    const size_t j0 = (size_t)(blockIdx.x % 48) * 16;
    const size_t i0 = (size_t)(blockIdx.x / 48) * 16;

    const float4* src = (const float4*)(mtr + ((i0 + r) * N + (j0 + c)) * 8);
    float4 a = src[0], b = src[1];
    *(float4*)&lds[r][c * 8 + 0] = a;
    *(float4*)&lds[r][c * 8 + 4] = b;
    __syncthreads();
    float4 ta = *(float4*)&lds[c][r * 8 + 0];
    float4 tb = *(float4*)&lds[c][r * 8 + 4];
    uint4 o;
    o.x = pk2(ta.x, ta.y); o.y = pk2(ta.z, ta.w);
    o.z = pk2(tb.x, tb.y); o.w = pk2(tb.z, tb.w);
    mtrT[(j0 + r) * N + (i0 + c)] = o;
  } else {
    const int t = (blockIdx.x - 2304) * 256 + threadIdx.x;  // < 430080 exact
    Mfrag4[t] = make_uint4(0, 0, 0, 0);  // NGROUPS*1024B / 16 = 430080
    if (t < 147456) winner4[t] = make_int4(-1, -1, -1, -1);
    if (t < NPAD_SLOTS) jlist[t] = 0;
    if (t < 1024) { deg[t] = 0; curs[t] = 0; }
    if (t == 0) *done_ctr = 0;
  }
}

// ---------------------------------------------------------------------------
// edge_prep + last-block fused scan: winner atomicMax, deg histogram;
// last-finishing block (ticket == 95) does the padded (ceil4) exclusive scan.
// ---------------------------------------------------------------------------
__global__ __launch_bounds__(256) void edge_prep_scan(
    const int* __restrict__ ei, int* __restrict__ winner,
    int* __restrict__ deg, int* __restrict__ offs,
    int* __restrict__ done_ctr) {
  const int e = blockIdx.x * 256 + threadIdx.x;  // grid 96*256 = E exact
  const int s = ei[e];
  const int d = ei[E + e];
  atomicMax(&winner[(size_t)s * N + d], e);
  atomicAdd(&deg[d], 1);

  __threadfence();
  __syncthreads();
  __shared__ int ticket;
  if (threadIdx.x == 0) ticket = atomicAdd(done_ctr, 1);
  __syncthreads();
  if (ticket == (E / 256) - 1 && threadIdx.x < 64) {
    const int lane = threadIdx.x;
    int v[12];
    int sum = 0;
#pragma unroll
    for (int z = 0; z < 12; ++z) {
      v[z] = (atomicAdd(&deg[lane * 12 + z], 0) + 3) & ~3;  // ceil4 pad
      sum += v[z];
    }
    int inc = sum;
#pragma unroll
    for (int dd = 1; dd < 64; dd <<= 1) {
      int t = __shfl_up(inc, dd, 64);
      if (lane >= dd) inc += t;
    }
    int run = inc - sum;
#pragma unroll
    for (int z = 0; z < 12; ++z) {
      run += v[z];
      offs[lane * 12 + z + 1] = run;
    }
    if (lane == 0) offs[0] = 0;
  }
}

// ---------------------------------------------------------------------------
// Edge MLP via MFMA with fused CSR scatter AND fused fragment repack.
// 4 waves/block, 16 edges/wave, 10 MFMAs/wave. Winner lanes claim CSR slots;
// layer-3 outputs bounce through LDS (stride-65, conflict-free) for the
// edge<->t lane transpose, then each winner writes its slot's disjoint 8B
// chunks of the group B-fragment directly (bit-identical to the old repack).
// Slot sg byte map inside a 1024B group fragment:
//   chunk(hl, t) @ (sg&1)*512 + hl*256 + t*16 + (sg>>1)*8,
//   holding pk2 pairs of M[hl*4+0..3][t].  Pad slots / t>=8 stay pre-zeroed.
// ---------------------------------------------------------------------------
__global__ __launch_bounds__(256) void edge_mlp_mfma(
    const float* __restrict__ feat, const int* __restrict__ ei,
    const float* __restrict__ ea, const int* __restrict__ winner,
    const int* __restrict__ offs, int* __restrict__ curs,
    int* __restrict__ jlist,
    const float* __restrict__ w0, const float* __restrict__ b0,
    const float* __restrict__ w1, const float* __restrict__ b1,
    const float* __restrict__ w2, const float* __restrict__ b2,
    const float* __restrict__ w3, const float* __restrict__ b3,
    short* __restrict__ Mfrag) {
  __shared__ float Ld[4][16 * 65];
  const int wv = threadIdx.x >> 6;
  const int lane = threadIdx.x & 63;
  const int col = lane & 15;
  const int hi = lane >> 4;
  const int e = (blockIdx.x * 4 + wv) * 16 + col;

  const float4 z4 = make_float4(0.f, 0.f, 0.f, 0.f);

  const int s = ei[e];
  const int d = ei[E + e];
  int pos = -1;
  if (hi == 0) {
    if (winner[(size_t)s * N + d] == e) {
      pos = offs[d] + atomicAdd(&curs[d], 1);
      jlist[pos] = s;
    }
  }
  pos = __shfl(pos, col, 64);

  const float* pa = (hi == 0) ? (ea + (size_t)e * 4)
                  : (hi == 1) ? (feat + (size_t)s * 8)
                  : (hi == 2) ? (feat + (size_t)s * 8 + 4)
                              : (feat + (size_t)d * 8);
  float4 va = *(const float4*)pa;
  float4 vb = (hi == 0) ? *(const float4*)(feat + (size_t)d * 8 + 4) : z4;
  bf16x8 bfr = pack_frag(va, vb);

  bf16x8 a0lo, a0hi, a1lo, a1hi, a2lo, a2hi, a3f[4];
  {
    const float* p = w0 + col * 20;
    float4 xa = *(const float4*)(p + hi * 4);
    float4 xb = (hi == 0) ? *(const float4*)(p + 16) : z4;
    a0lo = pack_frag(xa, xb);
    const float* q = w0 + (col + 16) * 20;
    float4 ya = *(const float4*)(q + hi * 4);
    float4 yb = (hi == 0) ? *(const float4*)(q + 16) : z4;
    a0hi = pack_frag(ya, yb);
  }
  a1lo = pack_frag(*(const float4*)(w1 + col * 32 + hi * 4),
                   *(const float4*)(w1 + col * 32 + 16 + hi * 4));
  a1hi = pack_frag(*(const float4*)(w1 + (col + 16) * 32 + hi * 4),
                   *(const float4*)(w1 + (col + 16) * 32 + 16 + hi * 4));
  a2lo = pack_frag(*(const float4*)(w2 + col * 32 + hi * 4),
                   *(const float4*)(w2 + col * 32 + 16 + hi * 4));
  a2hi = pack_frag(*(const float4*)(w2 + (col + 16) * 32 + hi * 4),
                   *(const float4*)(w2 + (col + 16) * 32 + 16 + hi * 4));
#pragma unroll
  for (int q = 0; q < 4; ++q) {
    const float* p = w3 + (size_t)(q * 16 + col) * 32;
    a3f[q] = pack_frag(*(const float4*)(p + hi * 4),
                       *(const float4*)(p + 16 + hi * 4));
  }

  f32x4 d1 = ld4(b0 + hi * 4), d2 = ld4(b0 + 16 + hi * 4);
  d1 = __builtin_amdgcn_mfma_f32_16x16x32_bf16(a0lo, bfr, d1, 0, 0, 0);
  d2 = __builtin_amdgcn_mfma_f32_16x16x32_bf16(a0hi, bfr, d2, 0, 0, 0);
  bfr = relu_pack(d1, d2);

  d1 = ld4(b1 + hi * 4); d2 = ld4(b1 + 16 + hi * 4);
  d1 = __builtin_amdgcn_mfma_f32_16x16x32_bf16(a1lo, bfr, d1, 0, 0, 0);
  d2 = __builtin_amdgcn_mfma_f32_16x16x32_bf16(a1hi, bfr, d2, 0, 0, 0);
  bfr = relu_pack(d1, d2);

  d1 = ld4(b2 + hi * 4); d2 = ld4(b2 + 16 + hi * 4);
  d1 = __builtin_amdgcn_mfma_f32_16x16x32_bf16(a2lo, bfr, d1, 0, 0, 0);
  d2 = __builtin_amdgcn_mfma_f32_16x16x32_bf16(a2hi, bfr, d2, 0, 0, 0);
  bfr = relu_pack(d1, d2);

  // ---- layer 3: D rows o = q*16 + hi*4 + r; park M[o = c*8+t] in LDS ----
#pragma unroll
  for (int q = 0; q < 4; ++q) {
    f32x4 d3 = ld4(b3 + q * 16 + hi * 4);
    d3 = __builtin_amdgcn_mfma_f32_16x16x32_bf16(a3f[q], bfr, d3, 0, 0, 0);
#pragma unroll
    for (int r = 0; r < 4; ++r)
      Ld[wv][col * 65 + q * 16 + hi * 4 + r] = d3[r];
  }
  __syncthreads();

  // ---- direct fragment write: lane hi handles hl = hi>>1, t = (hi&1)*4.. ----
  if (pos >= 0) {
    const int gid = pos >> 2;
    const int sg = pos & 3;
    short* base = Mfrag + (size_t)gid * 512 + (sg & 1) * 256 + (sg >> 1) * 4;
    const int hl = hi >> 1;
    const int t0 = (hi & 1) * 4;
    const float* m = &Ld[wv][col * 65];
#pragma unroll
    for (int cc = 0; cc < 4; ++cc) {
      const int t = t0 + cc;
      unsigned u0 = pk2(m[(hl * 4 + 0) * 8 + t], m[(hl * 4 + 1) * 8 + t]);
      unsigned u1 = pk2(m[(hl * 4 + 2) * 8 + t], m[(hl * 4 + 3) * 8 + t]);
      *(uint2*)(base + hl * 128 + t * 8) = make_uint2(u0, u1);
    }
  }
}

// ---------------------------------------------------------------------------
// Walk contraction v7 — MFMA, WT output in bf16 (unchanged from round 10).
// Block = 1 k x 256 i (4 waves x 4 D-tiles); XCD-chunked.
// ---------------------------------------------------------------------------
__global__ __launch_bounds__(256) void contract7(
    const short* __restrict__ mtrT, const short* __restrict__ Mfrag,
    const int* __restrict__ jlist, const int* __restrict__ offs,
    const int* __restrict__ wcnt, short* __restrict__ WTb) {
  __shared__ float sD[4][4][16][9];

  const int bid = blockIdx.x;
  const int g = (bid & 7) * 288 + (bid >> 3);  // XCD-chunked: 2304 = 8*288
  const int ig = g / 768;                      // i-slab 0..2 (256 i each)
  const int k = g % 768;
  const int w = threadIdx.x >> 6;
  const int lane = threadIdx.x & 63;
  const int col = lane & 15;
  const int hi = lane >> 4;
  const int ibase = ig * 256 + w * 64;

  const int base = offs[k];   // % 4 == 0 by construction
  const int cnt = wcnt[k];
  const int ngr = (cnt + 3) >> 2;

  f32x4 acc0 = {0.f, 0.f, 0.f, 0.f}, acc1 = {0.f, 0.f, 0.f, 0.f};
  f32x4 acc2 = {0.f, 0.f, 0.f, 0.f}, acc3 = {0.f, 0.f, 0.f, 0.f};

  const size_t lane_off = ((size_t)(ibase + col)) * 8 + (hi & 1) * 4;

#pragma unroll 1
  for (int gg = 0; gg < ngr; ++gg) {
    const int4 js = *(const int4*)(jlist + base + gg * 4);  // uniform
    const int ja = (hi & 2) ? js.y : js.x;
    const int jb = (hi & 2) ? js.w : js.z;

    bf16x8 bfr = *(const bf16x8*)(
        Mfrag + ((size_t)(base >> 2) + gg) * 512 + lane * 8);

    const short* pa = mtrT + (size_t)ja * (N * 8) + lane_off;
    const short* pb = mtrT + (size_t)jb * (N * 8) + lane_off;

#define TILE(ACC, T)                                                     \
  do {                                                                   \
    uint2 ua = *(const uint2*)(pa + (T) * (16 * 8));                     \
    uint2 ub = *(const uint2*)(pb + (T) * (16 * 8));                     \
    FragU af;                                                            \
    af.u[0] = ua.x; af.u[1] = ua.y; af.u[2] = ub.x; af.u[3] = ub.y;      \
    ACC = __builtin_amdgcn_mfma_f32_16x16x32_bf16(af.s, bfr, ACC, 0, 0, 0); \
  } while (0)

    TILE(acc0, 0);
    TILE(acc1, 1);
    TILE(acc2, 2);
    TILE(acc3, 3);
#undef TILE
  }

  // ---- epilogue: D lane (col=t, hi) holds D[i_loc=hi*4+r][t=col] ----
  if (col < 8) {
#pragma unroll
    for (int r = 0; r < 4; ++r) {
      sD[w][0][hi * 4 + r][col] = acc0[r] * 0.125f;
      sD[w][1][hi * 4 + r][col] = acc1[r] * 0.125f;
      sD[w][2][hi * 4 + r][col] = acc2[r] * 0.125f;
      sD[w][3][hi * 4 + r][col] = acc3[r] * 0.125f;
    }
  }
  __syncthreads();
  if (lane < 16) {
#pragma unroll
    for (int t = 0; t < 4; ++t) {
      const float* row = &sD[w][t][lane][0];
      uint4 o;
      o.x = pk2(row[0], row[1]); o.y = pk2(row[2], row[3]);
      o.z = pk2(row[4], row[5]); o.w = pk2(row[6], row[7]);
      *(uint4*)(WTb + ((size_t)k * N + ibase + t * 16 + lane) * 8) = o;
    }
  }
}

// ---------------------------------------------------------------------------
// Output MLP via MFMA (unchanged from round 10). WT read as bf16; one block
// per i, 12 k-groups per wave.
// ---------------------------------------------------------------------------
__global__ __launch_bounds__(256, 2) void out_mlp_mfma(
    const float* __restrict__ mtr, const short* __restrict__ WTb,
    const float* __restrict__ feat,
    const float* __restrict__ w0, const float* __restrict__ b0,
    const float* __restrict__ w1, const float* __restrict__ b1,
    const float* __restrict__ w2, const float* __restrict__ b2,
    const float* __restrict__ w3, const float* __restrict__ b3,
    float* __restrict__ out) {
  const int i = blockIdx.x;
  const int w = threadIdx.x >> 6;
  const int col = threadIdx.x & 15;
  const int hi = (threadIdx.x >> 4) & 3;

  bf16x8 a0lo, a0hi, a1lo, a1hi, a2lo, a2hi, a3;
  {
    const float* p = w0 + col * 33;
    float4 xa = make_float4(p[hi * 4], p[hi * 4 + 1], p[hi * 4 + 2], p[hi * 4 + 3]);
    float4 xb = make_float4(p[16 + hi * 4], p[16 + hi * 4 + 1],
                            p[16 + hi * 4 + 2], p[16 + hi * 4 + 3]);
    a0lo = pack_frag(xa, xb);
    const float* q = w0 + (col + 16) * 33;
    float4 ya = make_float4(q[hi * 4], q[hi * 4 + 1], q[hi * 4 + 2], q[hi * 4 + 3]);
    float4 yb = make_float4(q[16 + hi * 4], q[16 + hi * 4 + 1],
                            q[16 + hi * 4 + 2], q[16 + hi * 4 + 3]);
    a0hi = pack_frag(ya, yb);
  }
  a1lo = pack_frag(*(const float4*)(w1 + col * 32 + hi * 4),
                   *(const float4*)(w1 + col * 32 + 16 + hi * 4));
  a1hi = pack_frag(*(const float4*)(w1 + (col + 16) * 32 + hi * 4),
                   *(const float4*)(w1 + (col + 16) * 32 + 16 + hi * 4));
  a2lo = pack_frag(*(const float4*)(w2 + col * 32 + hi * 4),
                   *(const float4*)(w2 + col * 32 + 16 + hi * 4));
  a2hi = pack_frag(*(const float4*)(w2 + (col + 16) * 32 + hi * 4),
                   *(const float4*)(w2 + (col + 16) * 32 + 16 + hi * 4));
  if (col < 8) {
    a3 = pack_frag(*(const float4*)(w3 + col * 32 + hi * 4),
                   *(const float4*)(w3 + col * 32 + 16 + hi * 4));
  } else {
    FragU z; z.u[0] = z.u[1] = z.u[2] = z.u[3] = 0; a3 = z.s;
  }

  const f32x4 c1a = ld4(b0 + hi * 4), c1b = ld4(b0 + 16 + hi * 4);
  const f32x4 c2a = ld4(b1 + hi * 4), c2b = ld4(b1 + 16 + hi * 4);
  const f32x4 c3a = ld4(b2 + hi * 4), c3b = ld4(b2 + 16 + hi * 4);
  f32x4 c4;
  if (hi < 2) c4 = ld4(b3 + hi * 4);
  else { c4[0] = c4[1] = c4[2] = c4[3] = 0.f; }

  float dg1[4], dg2[4];
#pragma unroll
  for (int r = 0; r < 4; ++r) {
    dg1[r] = w0[(hi * 4 + r) * 33 + 32];
    dg2[r] = w0[(16 + hi * 4 + r) * 33 + 32];
  }

#pragma unroll 1
  for (int g = 0; g < 12; ++g) {
    const int krow = w * 192 + g * 16 + col;

    FragU bf;
    const short* pW = (hi < 2)
        ? (WTb + ((size_t)krow * N + i) * 8 + (hi & 1) * 4)
        : (WTb + ((size_t)i * N + krow) * 8 + (hi & 1) * 4);
    uint2 wv2 = *(const uint2*)pW;
    const float* pF = (hi < 2) ? (feat + (size_t)krow * 8 + (hi & 1) * 4)
                               : (feat + (size_t)i * 8 + (hi & 1) * 4);
    float4 fv = *(const float4*)pF;
    bf.u[0] = wv2.x; bf.u[1] = wv2.y;
    bf.u[2] = pk2(fv.x, fv.y); bf.u[3] = pk2(fv.z, fv.w);
    bf16x8 bfr = bf.s;

    f32x4 d1 = c1a, d2 = c1b;
    d1 = __builtin_amdgcn_mfma_f32_16x16x32_bf16(a0lo, bfr, d1, 0, 0, 0);
    d2 = __builtin_amdgcn_mfma_f32_16x16x32_bf16(a0hi, bfr, d2, 0, 0, 0);
    const float eye = (krow == i) ? 1.f : 0.f;
#pragma unroll
    for (int r = 0; r < 4; ++r) {
      d1[r] = fmaf(eye, dg1[r], d1[r]);
      d2[r] = fmaf(eye, dg2[r], d2[r]);
    }
    bfr = relu_pack(d1, d2);

    d1 = c2a; d2 = c2b;
    d1 = __builtin_amdgcn_mfma_f32_16x16x32_bf16(a1lo, bfr, d1, 0, 0, 0);
    d2 = __builtin_amdgcn_mfma_f32_16x16x32_bf16(a1hi, bfr, d2, 0, 0, 0);
    bfr = relu_pack(d1, d2);

    d1 = c3a; d2 = c3b;
    d1 = __builtin_amdgcn_mfma_f32_16x16x32_bf16(a2lo, bfr, d1, 0, 0, 0);
    d2 = __builtin_amdgcn_mfma_f32_16x16x32_bf16(a2hi, bfr, d2, 0, 0, 0);
    bfr = relu_pack(d1, d2);

    f32x4 d3 = c4;
    d3 = __builtin_amdgcn_mfma_f32_16x16x32_bf16(a3, bfr, d3, 0, 0, 0);

    if (hi < 2) {
      const size_t idx = ((size_t)i * N + krow) * 8 + hi * 4;
      float4 m = *(const float4*)(mtr + idx);
      *(float4*)(out + idx) =
          make_float4(m.x + d3[0], m.y + d3[1], m.z + d3[2], m.w + d3[3]);
    }
  }
}

// ---------------------------------------------------------------------------
extern "C" void kernel_launch(void* const* d_in, const int* in_sizes, int n_in,
                              void* d_out, int out_size, void* d_ws,
                              size_t ws_size, hipStream_t stream) {
  const float* mtr  = (const float*)d_in[0];
  const float* feat = (const float*)d_in[1];
  const int*   ei   = (const int*)d_in[2];
  const float* ea   = (const float*)d_in[3];
  const float* ew0 = (const float*)d_in[4];
  const float* eb0 = (const float*)d_in[5];
  const float* ew1 = (const float*)d_in[6];
  const float* eb1 = (const float*)d_in[7];
  const float* ew2 = (const float*)d_in[8];
  const float* eb2 = (const float*)d_in[9];
  const float* ew3 = (const float*)d_in[10];
  const float* eb3 = (const float*)d_in[11];
  const float* ow0 = (const float*)d_in[12];
  const float* ob0 = (const float*)d_in[13];
  const float* ow1 = (const float*)d_in[14];
  const float* ob1 = (const float*)d_in[15];
  const float* ow2 = (const float*)d_in[16];
  const float* ob2 = (const float*)d_in[17];
  const float* ow3 = (const float*)d_in[18];
  const float* ob3 = (const float*)d_in[19];
  float* out = (float*)d_out;

  char* ws = (char*)d_ws;
  short* Mfrag = (short*)ws; ws += (size_t)NGROUPS * 512 * 2;     // 6.88 MB
  short* mtrT  = (short*)ws; ws += (size_t)N * N * 8 * 2;         // 9.44 MB
  short* WTb   = (short*)ws; ws += (size_t)N * N * 8 * 2;         // 9.44 MB
  int* winner  = (int*)ws;   ws += (size_t)N * N * 4;             // 2.36 MB
  int* deg     = (int*)ws;   ws += 1024 * 4;
  int* offs    = (int*)ws;   ws += 1024 * 4;
  int* curs    = (int*)ws;   ws += 1024 * 4;
  int* done_ctr = (int*)ws;  ws += 256 * 4;
  int* jlist   = (int*)ws;   ws += (size_t)NPAD_SLOTS * 4;        // 108 KB

  prep0<<<2304 + 1680, 256, 0, stream>>>(mtr, (uint4*)mtrT, (int4*)winner,
                                         (uint4*)Mfrag, jlist, deg, curs,
                                         done_ctr);
  edge_prep_scan<<<E / 256, 256, 0, stream>>>(ei, winner, deg, offs, done_ctr);
  edge_mlp_mfma<<<E / 64, 256, 0, stream>>>(feat, ei, ea, winner, offs, curs,
                                            jlist, ew0, eb0, ew1, eb1, ew2,
                                            eb2, ew3, eb3, Mfrag);
  contract7<<<2304, 256, 0, stream>>>(mtrT, Mfrag, jlist, offs, curs, WTb);
  out_mlp_mfma<<<N, 256, 0, stream>>>(mtr, WTb, feat, ow0, ob0, ow1, ob1, ow2,
                                      ob2, ow3, ob3, out);
}